// Round 2
// baseline (1153.364 us; speedup 1.0000x reference)
//
#include <hip/hip_runtime.h>
#include <hip/hip_bf16.h>

// Transformer-XL relative multi-head attention.
// Inputs/outputs: float32 (per reference). Intermediates: bf16 in d_ws.
// B=8 T=1024 D_MODEL=512 H=8 DH=64.
// Pipeline: pos_kernel (P = pe @ Wpos), qkv_kernel (Qu,Qv,K,V), attn_kernel
// (fused flash w/ rel-shift index remap), out_kernel (Z @ Wout).
// Rel-shift identity: bd[t,s] = q_v[t] . p[(T-1) - t + s]  (l in [0,2046] always).

typedef unsigned short u16;

__device__ __forceinline__ float b2f(u16 u) {
    union { unsigned int i; float f; } x; x.i = ((unsigned int)u) << 16; return x.f;
}
__device__ __forceinline__ u16 f2b(float f) {
    __hip_bfloat16 h = __float2bfloat16(f);
    return *reinterpret_cast<u16*>(&h);
}

// ---------------------------------------------------------------- pos kernel
// P[h][l][d] = sum_k pe[l][k] * Wpos[k][h*64+d],  l = 0..2046, pos = l-1023
__global__ __launch_bounds__(256) void pos_kernel(const float* __restrict__ Wpos,
                                                  u16* __restrict__ P) {
    __shared__ float pe[8][512];
    const int tid = threadIdx.x;
    const int l0 = blockIdx.x * 8;
    // inv_freq[i] = 10000^(-i/256), i = tid
    float invf = expf(-9.210340371976184f * ((float)tid / 256.0f));
    for (int il = 0; il < 8; ++il) {
        int l = l0 + il; if (l > 2046) l = 2046;
        float ang = (float)(l - 1023) * invf;
        pe[il][2 * tid]     = sinf(ang);
        pe[il][2 * tid + 1] = cosf(ang);
    }
    __syncthreads();
    float acc[8][2];
    for (int il = 0; il < 8; ++il) { acc[il][0] = 0.f; acc[il][1] = 0.f; }
    for (int k = 0; k < 512; ++k) {
        float w0 = Wpos[k * 512 + tid];
        float w1 = Wpos[k * 512 + tid + 256];
#pragma unroll
        for (int il = 0; il < 8; ++il) {
            float pk = pe[il][k];
            acc[il][0] = fmaf(pk, w0, acc[il][0]);
            acc[il][1] = fmaf(pk, w1, acc[il][1]);
        }
    }
    for (int il = 0; il < 8; ++il) {
        int l = l0 + il; if (l >= 2047) break;
        int c0 = tid, c1 = tid + 256;
        P[((size_t)(c0 >> 6) * 2047 + l) * 64 + (c0 & 63)] = f2b(acc[il][0]);
        P[((size_t)(c1 >> 6) * 2047 + l) * 64 + (c1 & 63)] = f2b(acc[il][1]);
    }
}

// ---------------------------------------------------------------- qkv kernel
// 64x64 output tile per block, k-chunks of 32. Writes (b,h,t,d) layout bf16.
#define QLD 68
__global__ __launch_bounds__(256) void qkv_kernel(
    const float* __restrict__ xs, const float* __restrict__ Wq,
    const float* __restrict__ Wk, const float* __restrict__ Wv,
    const float* __restrict__ ub, const float* __restrict__ vb,
    u16* __restrict__ Qu, u16* __restrict__ Qv,
    u16* __restrict__ Kb, u16* __restrict__ Vb)
{
    __shared__ float xsT[32][QLD];     // [k][r]
    __shared__ float wt[3][32][QLD];   // [m][k][c]
    const int tid = threadIdx.x;
    const int r0 = blockIdx.x * 64;
    const int c0 = blockIdx.y * 64;
    const float* Wm[3] = {Wq, Wk, Wv};
    float acc[3][4][4];
    for (int m = 0; m < 3; ++m)
        for (int i = 0; i < 4; ++i)
            for (int j = 0; j < 4; ++j) acc[m][i][j] = 0.f;
    const int tr = tid >> 4, tc = tid & 15;

    for (int kc = 0; kc < 512; kc += 32) {
        __syncthreads();
        // stage xs transposed: 64 rows x 8 groups(4 k each)
        for (int it = 0; it < 2; ++it) {
            int gi = tid + (it << 8);          // 0..511
            int r = gi >> 3, g = gi & 7;
            float4 a = *(const float4*)&xs[(size_t)(r0 + r) * 512 + kc + 4 * g];
            xsT[4 * g + 0][r] = a.x;
            xsT[4 * g + 1][r] = a.y;
            xsT[4 * g + 2][r] = a.z;
            xsT[4 * g + 3][r] = a.w;
        }
        // stage W tiles: 32 k-rows x 16 col groups, x3
#pragma unroll
        for (int m = 0; m < 3; ++m) {
            for (int it = 0; it < 2; ++it) {
                int gi = tid + (it << 8);
                int kk = gi >> 4, g = gi & 15;
                float4 a = *(const float4*)&Wm[m][(size_t)(kc + kk) * 512 + c0 + 4 * g];
                wt[m][kk][4 * g + 0] = a.x;
                wt[m][kk][4 * g + 1] = a.y;
                wt[m][kk][4 * g + 2] = a.z;
                wt[m][kk][4 * g + 3] = a.w;
            }
        }
        __syncthreads();
        for (int kk = 0; kk < 32; ++kk) {
            float4 xa = *(float4*)&xsT[kk][4 * tr];
            float xav[4] = {xa.x, xa.y, xa.z, xa.w};
#pragma unroll
            for (int m = 0; m < 3; ++m) {
                float4 wb = *(float4*)&wt[m][kk][4 * tc];
                float wbv[4] = {wb.x, wb.y, wb.z, wb.w};
#pragma unroll
                for (int i = 0; i < 4; ++i)
#pragma unroll
                    for (int j = 0; j < 4; ++j)
                        acc[m][i][j] = fmaf(xav[i], wbv[j], acc[m][i][j]);
            }
        }
    }
    // epilogue: (b,h,t,d) layout, bias add for Qu/Qv, ushort4 stores
    for (int i = 0; i < 4; ++i) {
        int r = r0 + 4 * tr + i;
        int b = r >> 10, t = r & 1023;
        int c = c0 + 4 * tc;
        int h = c >> 6, d = c & 63;
        size_t o = (((size_t)b * 8 + h) * 1024 + t) * 64 + d;
        ushort4 sk, sv, squ, sqv;
        sk.x = f2b(acc[1][i][0]); sk.y = f2b(acc[1][i][1]);
        sk.z = f2b(acc[1][i][2]); sk.w = f2b(acc[1][i][3]);
        sv.x = f2b(acc[2][i][0]); sv.y = f2b(acc[2][i][1]);
        sv.z = f2b(acc[2][i][2]); sv.w = f2b(acc[2][i][3]);
        squ.x = f2b(acc[0][i][0] + ub[c + 0]);
        squ.y = f2b(acc[0][i][1] + ub[c + 1]);
        squ.z = f2b(acc[0][i][2] + ub[c + 2]);
        squ.w = f2b(acc[0][i][3] + ub[c + 3]);
        sqv.x = f2b(acc[0][i][0] + vb[c + 0]);
        sqv.y = f2b(acc[0][i][1] + vb[c + 1]);
        sqv.z = f2b(acc[0][i][2] + vb[c + 2]);
        sqv.w = f2b(acc[0][i][3] + vb[c + 3]);
        *(ushort4*)&Kb[o] = sk;
        *(ushort4*)&Vb[o] = sv;
        *(ushort4*)&Qu[o] = squ;
        *(ushort4*)&Qv[o] = sqv;
    }
}

// ---------------------------------------------------------------- attention
// One block = (b, h, 16 query rows). S-chunks of 32, online softmax.
// p-band row index: poff = 15 - row + sl  in [0,46] -> stage 48 rows.
#define SD 68
__global__ __launch_bounds__(256) void attn_kernel(
    const u16* __restrict__ Qu, const u16* __restrict__ Qv,
    const u16* __restrict__ Kb, const u16* __restrict__ Vb,
    const u16* __restrict__ P, const int* __restrict__ mask,
    u16* __restrict__ Z)
{
    __shared__ float qu[16][SD], qv[16][SD];
    __shared__ float kt[32][SD], vt[32][SD];
    __shared__ float pt[48][SD];
    __shared__ float sc[16][SD];
    __shared__ float mrun[16], lrun[16], aLDS[16];

    const int tid = threadIdx.x;
    const int bid = blockIdx.x;
    const int t0 = (bid & 63) << 4;
    const int h  = (bid >> 6) & 7;
    const int b  = bid >> 9;
    const size_t bh = ((size_t)b * 8 + h) * 1024;

    {
        int row = tid >> 4, g = tid & 15;
        ushort4 a = *(const ushort4*)&Qu[(bh + t0 + row) * 64 + 4 * g];
        ushort4 c = *(const ushort4*)&Qv[(bh + t0 + row) * 64 + 4 * g];
        qu[row][4 * g + 0] = b2f(a.x); qu[row][4 * g + 1] = b2f(a.y);
        qu[row][4 * g + 2] = b2f(a.z); qu[row][4 * g + 3] = b2f(a.w);
        qv[row][4 * g + 0] = b2f(c.x); qv[row][4 * g + 1] = b2f(c.y);
        qv[row][4 * g + 2] = b2f(c.z); qv[row][4 * g + 3] = b2f(c.w);
    }
    if (tid < 16) { mrun[tid] = -3.0e38f; lrun[tid] = 0.f; }
    const int row = tid >> 4, g = tid & 15;
    const int sl0 = g, sl1 = g + 16;
    const int po0 = 15 - row + sl0, po1 = 15 - row + sl1;
    float o0 = 0.f, o1 = 0.f, o2 = 0.f, o3 = 0.f;

    for (int s0 = 0; s0 < 1024; s0 += 32) {
        __syncthreads();
        // stage K,V chunk: 32 rows x 16 groups
        for (int it = 0; it < 2; ++it) {
            int gi = tid + (it << 8);
            int r = gi >> 4, gg = gi & 15;
            ushort4 a = *(const ushort4*)&Kb[(bh + s0 + r) * 64 + 4 * gg];
            kt[r][4 * gg + 0] = b2f(a.x); kt[r][4 * gg + 1] = b2f(a.y);
            kt[r][4 * gg + 2] = b2f(a.z); kt[r][4 * gg + 3] = b2f(a.w);
            ushort4 c = *(const ushort4*)&Vb[(bh + s0 + r) * 64 + 4 * gg];
            vt[r][4 * gg + 0] = b2f(c.x); vt[r][4 * gg + 1] = b2f(c.y);
            vt[r][4 * gg + 2] = b2f(c.z); vt[r][4 * gg + 3] = b2f(c.w);
        }
        // stage P band: rows lbase..lbase+47 (row 47 unused; clamp keeps in-bounds)
        int lbase = 1008 - t0 + s0;
        for (int it = 0; it < 3; ++it) {
            int gi = tid + (it << 8);          // 0..767
            int r = gi >> 4, gg = gi & 15;     // r < 48
            int l = lbase + r; if (l > 2046) l = 2046;
            ushort4 a = *(const ushort4*)&P[((size_t)h * 2047 + l) * 64 + 4 * gg];
            pt[r][4 * gg + 0] = b2f(a.x); pt[r][4 * gg + 1] = b2f(a.y);
            pt[r][4 * gg + 2] = b2f(a.z); pt[r][4 * gg + 3] = b2f(a.w);
        }
        __syncthreads();
        // scores: 2 per thread
        float sa0 = 0.f, sa1 = 0.f;
#pragma unroll 4
        for (int d4 = 0; d4 < 16; ++d4) {
            float4 uq = *(float4*)&qu[row][4 * d4];
            float4 vq = *(float4*)&qv[row][4 * d4];
            float4 k0 = *(float4*)&kt[sl0][4 * d4];
            float4 p0 = *(float4*)&pt[po0][4 * d4];
            float4 k1 = *(float4*)&kt[sl1][4 * d4];
            float4 p1 = *(float4*)&pt[po1][4 * d4];
            sa0 += uq.x * k0.x + uq.y * k0.y + uq.z * k0.z + uq.w * k0.w
                 + vq.x * p0.x + vq.y * p0.y + vq.z * p0.z + vq.w * p0.w;
            sa1 += uq.x * k1.x + uq.y * k1.y + uq.z * k1.z + uq.w * k1.w
                 + vq.x * p1.x + vq.y * p1.y + vq.z * p1.z + vq.w * p1.w;
        }
        const int* mrow = &mask[((size_t)b * 1024 + t0 + row) * 1024 + s0];
        int m0v = mrow[sl0], m1v = mrow[sl1];
        sa0 = (m0v == 0) ? -1.0e30f : sa0 * 0.125f;
        sa1 = (m1v == 0) ? -1.0e30f : sa1 * 0.125f;
        sc[row][sl0] = sa0;
        sc[row][sl1] = sa1;
        __syncthreads();
        // online softmax state update (one thread per row)
        if (tid < 16) {
            float mold = mrun[tid], mx = mold;
            for (int s = 0; s < 32; ++s) mx = fmaxf(mx, sc[tid][s]);
            float al = __expf(mold - mx);
            float ls = 0.f;
            for (int s = 0; s < 32; ++s) {
                float e = __expf(sc[tid][s] - mx);
                sc[tid][s] = e; ls += e;
            }
            lrun[tid] = lrun[tid] * al + ls;
            mrun[tid] = mx;
            aLDS[tid] = al;
        }
        __syncthreads();
        // PV accumulate
        float al = aLDS[row];
        o0 *= al; o1 *= al; o2 *= al; o3 *= al;
#pragma unroll 8
        for (int s = 0; s < 32; ++s) {
            float e = sc[row][s];
            float4 vv = *(float4*)&vt[s][4 * g];
            o0 = fmaf(e, vv.x, o0);
            o1 = fmaf(e, vv.y, o1);
            o2 = fmaf(e, vv.z, o2);
            o3 = fmaf(e, vv.w, o3);
        }
    }
    float inv = 1.0f / lrun[row];
    // Z[b][t][h*64+d]
    size_t zo = ((((size_t)b << 10) + t0 + row) << 9) + (h << 6) + 4 * g;
    ushort4 zs;
    zs.x = f2b(o0 * inv); zs.y = f2b(o1 * inv);
    zs.z = f2b(o2 * inv); zs.w = f2b(o3 * inv);
    *(ushort4*)&Z[zo] = zs;
}

// ---------------------------------------------------------------- out proj
__global__ __launch_bounds__(256) void out_kernel(
    const u16* __restrict__ Zin, const float* __restrict__ Wout,
    float* __restrict__ out)
{
    __shared__ float zT[32][QLD];
    __shared__ float wt[32][QLD];
    const int tid = threadIdx.x;
    const int r0 = blockIdx.x * 64;
    const int c0 = blockIdx.y * 64;
    float acc[4][4];
    for (int i = 0; i < 4; ++i)
        for (int j = 0; j < 4; ++j) acc[i][j] = 0.f;
    const int tr = tid >> 4, tc = tid & 15;

    for (int kc = 0; kc < 512; kc += 32) {
        __syncthreads();
        for (int it = 0; it < 2; ++it) {
            int gi = tid + (it << 8);
            int r = gi >> 3, g = gi & 7;
            ushort4 a = *(const ushort4*)&Zin[(size_t)(r0 + r) * 512 + kc + 4 * g];
            zT[4 * g + 0][r] = b2f(a.x);
            zT[4 * g + 1][r] = b2f(a.y);
            zT[4 * g + 2][r] = b2f(a.z);
            zT[4 * g + 3][r] = b2f(a.w);
        }
        for (int it = 0; it < 2; ++it) {
            int gi = tid + (it << 8);
            int kk = gi >> 4, g = gi & 15;
            float4 a = *(const float4*)&Wout[(size_t)(kc + kk) * 512 + c0 + 4 * g];
            wt[kk][4 * g + 0] = a.x;
            wt[kk][4 * g + 1] = a.y;
            wt[kk][4 * g + 2] = a.z;
            wt[kk][4 * g + 3] = a.w;
        }
        __syncthreads();
        for (int kk = 0; kk < 32; ++kk) {
            float4 xa = *(float4*)&zT[kk][4 * tr];
            float4 wb = *(float4*)&wt[kk][4 * tc];
            float xav[4] = {xa.x, xa.y, xa.z, xa.w};
            float wbv[4] = {wb.x, wb.y, wb.z, wb.w};
#pragma unroll
            for (int i = 0; i < 4; ++i)
#pragma unroll
                for (int j = 0; j < 4; ++j)
                    acc[i][j] = fmaf(xav[i], wbv[j], acc[i][j]);
        }
    }
    for (int i = 0; i < 4; ++i) {
        int r = r0 + 4 * tr + i;
        float4 s;
        s.x = acc[i][0]; s.y = acc[i][1];
        s.z = acc[i][2]; s.w = acc[i][3];
        *(float4*)&out[(size_t)r * 512 + c0 + 4 * tc] = s;
    }
}

// ---------------------------------------------------------------- launch
extern "C" void kernel_launch(void* const* d_in, const int* in_sizes, int n_in,
                              void* d_out, int out_size, void* d_ws, size_t ws_size,
                              hipStream_t stream) {
    const float* xs   = (const float*)d_in[0];
    const int*   mask = (const int*)d_in[1];
    const float* Wq   = (const float*)d_in[2];
    const float* Wk   = (const float*)d_in[3];
    const float* Wv   = (const float*)d_in[4];
    const float* Wpos = (const float*)d_in[5];
    const float* Wout = (const float*)d_in[6];
    const float* ub   = (const float*)d_in[7];
    const float* vb   = (const float*)d_in[8];
    float* out = (float*)d_out;

    // workspace layout (bf16 elements)
    u16* Qu = (u16*)d_ws;                    // 8*8*1024*64 = 4194304
    u16* Qv = Qu + 4194304;
    u16* Kb = Qv + 4194304;
    u16* Vb = Kb + 4194304;
    u16* P  = Vb + 4194304;                  // 8*2047*64 = 1048064 (pad to 1048576)
    u16* Z  = P + 1048576;                   // 4194304

    pos_kernel<<<256, 256, 0, stream>>>(Wpos, P);
    qkv_kernel<<<dim3(128, 8), 256, 0, stream>>>(xs, Wq, Wk, Wv, ub, vb, Qu, Qv, Kb, Vb);
    attn_kernel<<<4096, 256, 0, stream>>>(Qu, Qv, Kb, Vb, P, mask, Z);
    out_kernel<<<dim3(128, 8), 256, 0, stream>>>(Z, Wout, out);
}

// Round 3
// 478.085 us; speedup vs baseline: 2.4125x; 2.4125x over previous
//
#include <hip/hip_runtime.h>
#include <hip/hip_bf16.h>

// Transformer-XL relative MHA. fp32 in/out, bf16 intermediates in d_ws.
// B=8 T=1024 D_MODEL=512 H=8 DH=64.
// attn_mfma: S^T formulation, 16x16x32 bf16 MFMA, flash online-softmax.
// Rel-shift identity: bd[t,s] = q_v[t] . p[1023 - t + s].

typedef unsigned short u16;
typedef __attribute__((ext_vector_type(8))) short bf16x8;
typedef __attribute__((ext_vector_type(8))) unsigned short ushort8v;
typedef __attribute__((ext_vector_type(4))) float floatx4;

__device__ __forceinline__ float b2f(u16 u) {
    union { unsigned int i; float f; } x; x.i = ((unsigned int)u) << 16; return x.f;
}
__device__ __forceinline__ u16 f2b(float f) {
    __hip_bfloat16 h = __float2bfloat16(f);
    return *reinterpret_cast<u16*>(&h);
}

#define MFMA16(a, b, c) __builtin_amdgcn_mfma_f32_16x16x32_bf16(a, b, c, 0, 0, 0)

// ---------------------------------------------------------------- pos kernel
// P[h][l][d] = sum_k pe[l][k] * Wpos[k][h*64+d],  l = 0..2046, pos = l-1023
__global__ __launch_bounds__(256) void pos_kernel(const float* __restrict__ Wpos,
                                                  u16* __restrict__ P) {
    __shared__ float pe[8][512];
    const int tid = threadIdx.x;
    const int l0 = blockIdx.x * 8;
    float invf = expf(-9.210340371976184f * ((float)tid / 256.0f));
    for (int il = 0; il < 8; ++il) {
        int l = l0 + il; if (l > 2046) l = 2046;
        float ang = (float)(l - 1023) * invf;
        pe[il][2 * tid]     = sinf(ang);
        pe[il][2 * tid + 1] = cosf(ang);
    }
    __syncthreads();
    float acc[8][2];
    for (int il = 0; il < 8; ++il) { acc[il][0] = 0.f; acc[il][1] = 0.f; }
    for (int k = 0; k < 512; ++k) {
        float w0 = Wpos[k * 512 + tid];
        float w1 = Wpos[k * 512 + tid + 256];
#pragma unroll
        for (int il = 0; il < 8; ++il) {
            float pk = pe[il][k];
            acc[il][0] = fmaf(pk, w0, acc[il][0]);
            acc[il][1] = fmaf(pk, w1, acc[il][1]);
        }
    }
    for (int il = 0; il < 8; ++il) {
        int l = l0 + il; if (l >= 2047) break;
        int c0 = tid, c1 = tid + 256;
        P[((size_t)(c0 >> 6) * 2047 + l) * 64 + (c0 & 63)] = f2b(acc[il][0]);
        P[((size_t)(c1 >> 6) * 2047 + l) * 64 + (c1 & 63)] = f2b(acc[il][1]);
    }
}

// ---------------------------------------------------------------- qkv kernel
// 64x64 tile per block. Writes Qu,Qv,K in (b,h,t,d); V transposed (b,h,d,t).
#define QLD 68
__global__ __launch_bounds__(256) void qkv_kernel(
    const float* __restrict__ xs, const float* __restrict__ Wq,
    const float* __restrict__ Wk, const float* __restrict__ Wv,
    const float* __restrict__ ub, const float* __restrict__ vb,
    u16* __restrict__ Qu, u16* __restrict__ Qv,
    u16* __restrict__ Kb, u16* __restrict__ Vtg)
{
    __shared__ float xsT[32][QLD];
    __shared__ float wt[3][32][QLD];
    const int tid = threadIdx.x;
    const int r0 = blockIdx.x * 64;
    const int c0 = blockIdx.y * 64;
    const float* Wm[3] = {Wq, Wk, Wv};
    float acc[3][4][4];
    for (int m = 0; m < 3; ++m)
        for (int i = 0; i < 4; ++i)
            for (int j = 0; j < 4; ++j) acc[m][i][j] = 0.f;
    const int tr = tid >> 4, tc = tid & 15;

    for (int kc = 0; kc < 512; kc += 32) {
        __syncthreads();
        for (int it = 0; it < 2; ++it) {
            int gi = tid + (it << 8);
            int r = gi >> 3, g = gi & 7;
            float4 a = *(const float4*)&xs[(size_t)(r0 + r) * 512 + kc + 4 * g];
            xsT[4 * g + 0][r] = a.x;
            xsT[4 * g + 1][r] = a.y;
            xsT[4 * g + 2][r] = a.z;
            xsT[4 * g + 3][r] = a.w;
        }
#pragma unroll
        for (int m = 0; m < 3; ++m) {
            for (int it = 0; it < 2; ++it) {
                int gi = tid + (it << 8);
                int kk = gi >> 4, g = gi & 15;
                float4 a = *(const float4*)&Wm[m][(size_t)(kc + kk) * 512 + c0 + 4 * g];
                wt[m][kk][4 * g + 0] = a.x;
                wt[m][kk][4 * g + 1] = a.y;
                wt[m][kk][4 * g + 2] = a.z;
                wt[m][kk][4 * g + 3] = a.w;
            }
        }
        __syncthreads();
        for (int kk = 0; kk < 32; ++kk) {
            float4 xa = *(float4*)&xsT[kk][4 * tr];
            float xav[4] = {xa.x, xa.y, xa.z, xa.w};
#pragma unroll
            for (int m = 0; m < 3; ++m) {
                float4 wb = *(float4*)&wt[m][kk][4 * tc];
                float wbv[4] = {wb.x, wb.y, wb.z, wb.w};
#pragma unroll
                for (int i = 0; i < 4; ++i)
#pragma unroll
                    for (int j = 0; j < 4; ++j)
                        acc[m][i][j] = fmaf(xav[i], wbv[j], acc[m][i][j]);
            }
        }
    }
    // epilogue
    const int bq = r0 >> 10;
    const int hq = c0 >> 6;
    const int tb = (r0 & 1023) + 4 * tr;
    for (int i = 0; i < 4; ++i) {
        int c = c0 + 4 * tc;
        int d = 4 * tc;
        size_t o = (((size_t)bq * 8 + hq) * 1024 + tb + i) * 64 + d;
        ushort4 sk, squ, sqv;
        sk.x = f2b(acc[1][i][0]); sk.y = f2b(acc[1][i][1]);
        sk.z = f2b(acc[1][i][2]); sk.w = f2b(acc[1][i][3]);
        squ.x = f2b(acc[0][i][0] + ub[c + 0]);
        squ.y = f2b(acc[0][i][1] + ub[c + 1]);
        squ.z = f2b(acc[0][i][2] + ub[c + 2]);
        squ.w = f2b(acc[0][i][3] + ub[c + 3]);
        sqv.x = f2b(acc[0][i][0] + vb[c + 0]);
        sqv.y = f2b(acc[0][i][1] + vb[c + 1]);
        sqv.z = f2b(acc[0][i][2] + vb[c + 2]);
        sqv.w = f2b(acc[0][i][3] + vb[c + 3]);
        *(ushort4*)&Kb[o] = sk;
        *(ushort4*)&Qu[o] = squ;
        *(ushort4*)&Qv[o] = sqv;
    }
    // V transposed: Vtg[(b,h,d)][t], 4 consecutive t per store
    for (int j = 0; j < 4; ++j) {
        int d = 4 * tc + j;
        ushort4 sv;
        sv.x = f2b(acc[2][0][j]); sv.y = f2b(acc[2][1][j]);
        sv.z = f2b(acc[2][2][j]); sv.w = f2b(acc[2][3][j]);
        *(ushort4*)&Vtg[(((size_t)bq * 8 + hq) * 64 + d) * 1024 + tb] = sv;
    }
}

// ---------------------------------------------------------------- attention
// Block = (b, h, 64 q-rows) = 4 waves x 16 rows. S-chunks of 64.
// S^T formulation: rows = ss, cols = tt. Qu/Qv are register B-fragments.
__global__ __launch_bounds__(256, 2) void attn_mfma(
    const u16* __restrict__ Qu, const u16* __restrict__ Qv,
    const u16* __restrict__ Kb, const u16* __restrict__ Vtg,
    const u16* __restrict__ P, const int* __restrict__ mask,
    u16* __restrict__ Z)
{
    __shared__ u16 Klds[64 * 72];          // [s][d] stride 72
    __shared__ u16 Vtlds[64 * 72];         // [d][s] stride 72
    __shared__ u16 Pb[128 * 64];           // [j][d] XOR-swizzled 16B blocks
    __shared__ unsigned long long Mrow[64];
    __shared__ float Gl[4][16 * 80];       // per wave: [tt][j] stride 80
    __shared__ u16 Prob[4][16 * 72];       // per wave: [tt][ss] stride 72

    const int tid  = threadIdx.x;
    const int lane = tid & 63;
    const int w    = tid >> 6;
    const int quad = lane >> 4;
    const int ln   = lane & 15;

    const int bid = blockIdx.x;
    const int t0 = (bid & 15) << 6;
    const int h  = (bid >> 4) & 7;
    const int b  = bid >> 7;
    const size_t bh  = ((size_t)b * 8 + h) * 1024;  // t-major base
    const size_t bhd = ((size_t)b * 8 + h) * 64;    // d-major base (Vtg)

    // register B-fragments: Qu/Qv rows of this wave (t = t0+16w+ln)
    const size_t qoff = (bh + t0 + 16 * w + ln) * 64;
    const bf16x8 qu0 = *(const bf16x8*)&Qu[qoff + quad * 8];
    const bf16x8 qu1 = *(const bf16x8*)&Qu[qoff + 32 + quad * 8];
    const bf16x8 qv0 = *(const bf16x8*)&Qv[qoff + quad * 8];
    const bf16x8 qv1 = *(const bf16x8*)&Qv[qoff + 32 + quad * 8];

    floatx4 O0 = {0.f, 0.f, 0.f, 0.f}, O1 = O0, O2 = O0, O3 = O0;
    float m_run = -3.0e38f, l_run = 0.f;

    for (int s0 = 0; s0 < 1024; s0 += 64) {
        __syncthreads();
        // ---- stage K rows (s) and Vt rows (d)
#pragma unroll
        for (int it = 0; it < 2; ++it) {
            int idx = tid + (it << 8);
            int r = idx >> 3, g = idx & 7;
            *(ushort8v*)&Klds[r * 72 + g * 8] =
                *(const ushort8v*)&Kb[(bh + s0 + r) * 64 + g * 8];
            *(ushort8v*)&Vtlds[r * 72 + g * 8] =
                *(const ushort8v*)&Vtg[(bhd + r) * 1024 + s0 + g * 8];
        }
        // ---- stage P band: rows l = lb0 .. lb0+127 (always in [0,2046] except pad row)
        const int lb0 = 960 - t0 + s0;
#pragma unroll
        for (int it = 0; it < 4; ++it) {
            int idx = tid + (it << 8);
            int r = idx >> 3, g = idx & 7;
            int l = lb0 + r; if (l > 2046) l = 2046;
            *(ushort8v*)&Pb[r * 64 + (((g ^ (r & 7))) << 3)] =
                *(const ushort8v*)&P[((size_t)h * 2047 + l) * 64 + g * 8];
        }
        // ---- stage mask as per-row 64-bit ballots (wave w: block rows 16w..16w+15)
        {
            int mv[16];
#pragma unroll
            for (int rr = 0; rr < 16; ++rr)
                mv[rr] = mask[((size_t)b * 1024 + t0 + 16 * w + rr) * 1024 + s0 + lane];
#pragma unroll
            for (int rr = 0; rr < 16; ++rr) {
                unsigned long long bits = __ballot(mv[rr] != 0);
                if (lane == 0) Mrow[16 * w + rr] = bits;
            }
        }
        __syncthreads();

        // ---- BD: G^T[j][tt] = Pband . Qv^T   (5 j-tiles, j = ss - tt + 15)
        float* gw = &Gl[w][0];
#pragma unroll
        for (int jt = 0; jt < 5; ++jt) {
            int jr = 48 - 16 * w + jt * 16 + ln;
            floatx4 g = {0.f, 0.f, 0.f, 0.f};
            bf16x8 a0 = *(bf16x8*)&Pb[jr * 64 + ((quad ^ (jr & 7)) << 3)];
            bf16x8 a1 = *(bf16x8*)&Pb[jr * 64 + (((4 + quad) ^ (jr & 7)) << 3)];
            g = MFMA16(a0, qv0, g);
            g = MFMA16(a1, qv1, g);
            // C-frag: col=tt=ln, rows j = jt*16+quad*4+reg -> write G[tt][j] packed
            *(floatx4*)&gw[ln * 80 + jt * 16 + quad * 4] = g;
        }
        // ---- AC: S^T[ss][tt] = K . Qu^T
        floatx4 cac[4];
#pragma unroll
        for (int st = 0; st < 4; ++st) {
            floatx4 c = {0.f, 0.f, 0.f, 0.f};
            int kr = st * 16 + ln;
            bf16x8 a0 = *(bf16x8*)&Klds[kr * 72 + quad * 8];
            bf16x8 a1 = *(bf16x8*)&Klds[kr * 72 + 32 + quad * 8];
            c = MFMA16(a0, qu0, c);
            c = MFMA16(a1, qu1, c);
            cac[st] = c;
        }
        // ---- scores + online softmax (lane owns col tt = ln; rows ss across regs)
        const unsigned long long bits = Mrow[16 * w + ln];
        float sc[4][4];
        float cmax = -3.0e38f;
#pragma unroll
        for (int st = 0; st < 4; ++st) {
            int j0 = st * 16 + quad * 4 + 15 - ln;
#pragma unroll
            for (int r = 0; r < 4; ++r) {
                float v = (cac[st][r] + gw[ln * 80 + j0 + r]) * 0.125f;
                int ss = st * 16 + quad * 4 + r;
                v = ((bits >> ss) & 1ull) ? v : -1.0e30f;
                sc[st][r] = v;
                cmax = fmaxf(cmax, v);
            }
        }
        cmax = fmaxf(cmax, __shfl_xor(cmax, 16));
        cmax = fmaxf(cmax, __shfl_xor(cmax, 32));
        float m_new = fmaxf(m_run, cmax);
        float alpha = __expf(m_run - m_new);
        float psum = 0.f;
#pragma unroll
        for (int st = 0; st < 4; ++st) {
            float p0 = __expf(sc[st][0] - m_new);
            float p1 = __expf(sc[st][1] - m_new);
            float p2 = __expf(sc[st][2] - m_new);
            float p3 = __expf(sc[st][3] - m_new);
            psum += (p0 + p1) + (p2 + p3);
            ushort4 pk;
            pk.x = f2b(p0); pk.y = f2b(p1); pk.z = f2b(p2); pk.w = f2b(p3);
            *(ushort4*)&Prob[w][ln * 72 + st * 16 + quad * 4] = pk;
        }
        psum += __shfl_xor(psum, 16);
        psum += __shfl_xor(psum, 32);
        l_run = l_run * alpha + psum;
        m_run = m_new;
        // ---- rescale O by alpha (O rows = quad*4+reg; alpha lives at lane ln=row)
        float a0s = __shfl(alpha, quad * 4 + 0);
        float a1s = __shfl(alpha, quad * 4 + 1);
        float a2s = __shfl(alpha, quad * 4 + 2);
        float a3s = __shfl(alpha, quad * 4 + 3);
        O0[0] *= a0s; O0[1] *= a1s; O0[2] *= a2s; O0[3] *= a3s;
        O1[0] *= a0s; O1[1] *= a1s; O1[2] *= a2s; O1[3] *= a3s;
        O2[0] *= a0s; O2[1] *= a1s; O2[2] *= a2s; O2[3] *= a3s;
        O3[0] *= a0s; O3[1] *= a1s; O3[2] *= a2s; O3[3] *= a3s;
        // ---- PV: O[t][d] += Prob . V  (A = probs, Bt = Vt rows)
        bf16x8 pa0 = *(bf16x8*)&Prob[w][ln * 72 + quad * 8];
        bf16x8 pa1 = *(bf16x8*)&Prob[w][ln * 72 + 32 + quad * 8];
        {
            bf16x8 v0 = *(bf16x8*)&Vtlds[(0 + ln) * 72 + quad * 8];
            bf16x8 v1 = *(bf16x8*)&Vtlds[(0 + ln) * 72 + 32 + quad * 8];
            O0 = MFMA16(pa0, v0, O0); O0 = MFMA16(pa1, v1, O0);
        }
        {
            bf16x8 v0 = *(bf16x8*)&Vtlds[(16 + ln) * 72 + quad * 8];
            bf16x8 v1 = *(bf16x8*)&Vtlds[(16 + ln) * 72 + 32 + quad * 8];
            O1 = MFMA16(pa0, v0, O1); O1 = MFMA16(pa1, v1, O1);
        }
        {
            bf16x8 v0 = *(bf16x8*)&Vtlds[(32 + ln) * 72 + quad * 8];
            bf16x8 v1 = *(bf16x8*)&Vtlds[(32 + ln) * 72 + 32 + quad * 8];
            O2 = MFMA16(pa0, v0, O2); O2 = MFMA16(pa1, v1, O2);
        }
        {
            bf16x8 v0 = *(bf16x8*)&Vtlds[(48 + ln) * 72 + quad * 8];
            bf16x8 v1 = *(bf16x8*)&Vtlds[(48 + ln) * 72 + 32 + quad * 8];
            O3 = MFMA16(pa0, v0, O3); O3 = MFMA16(pa1, v1, O3);
        }
    }
    // ---- epilogue: O rows = t0+16w+quad*4+reg, cols d = dt*16+ln
    float li0 = 1.0f / __shfl(l_run, quad * 4 + 0);
    float li1 = 1.0f / __shfl(l_run, quad * 4 + 1);
    float li2 = 1.0f / __shfl(l_run, quad * 4 + 2);
    float li3 = 1.0f / __shfl(l_run, quad * 4 + 3);
    float li[4] = {li0, li1, li2, li3};
#pragma unroll
    for (int r = 0; r < 4; ++r) {
        size_t zo = ((size_t)b * 1024 + t0 + 16 * w + quad * 4 + r) * 512 + h * 64 + ln;
        Z[zo + 0]  = f2b(O0[r] * li[r]);
        Z[zo + 16] = f2b(O1[r] * li[r]);
        Z[zo + 32] = f2b(O2[r] * li[r]);
        Z[zo + 48] = f2b(O3[r] * li[r]);
    }
}

// ---------------------------------------------------------------- out proj
__global__ __launch_bounds__(256) void out_kernel(
    const u16* __restrict__ Zin, const float* __restrict__ Wout,
    float* __restrict__ out)
{
    __shared__ float zT[32][QLD];
    __shared__ float wt[32][QLD];
    const int tid = threadIdx.x;
    const int r0 = blockIdx.x * 64;
    const int c0 = blockIdx.y * 64;
    float acc[4][4];
    for (int i = 0; i < 4; ++i)
        for (int j = 0; j < 4; ++j) acc[i][j] = 0.f;
    const int tr = tid >> 4, tc = tid & 15;

    for (int kc = 0; kc < 512; kc += 32) {
        __syncthreads();
        for (int it = 0; it < 2; ++it) {
            int gi = tid + (it << 8);
            int r = gi >> 3, g = gi & 7;
            ushort4 a = *(const ushort4*)&Zin[(size_t)(r0 + r) * 512 + kc + 4 * g];
            zT[4 * g + 0][r] = b2f(a.x);
            zT[4 * g + 1][r] = b2f(a.y);
            zT[4 * g + 2][r] = b2f(a.z);
            zT[4 * g + 3][r] = b2f(a.w);
        }
        for (int it = 0; it < 2; ++it) {
            int gi = tid + (it << 8);
            int kk = gi >> 4, g = gi & 15;
            float4 a = *(const float4*)&Wout[(size_t)(kc + kk) * 512 + c0 + 4 * g];
            wt[kk][4 * g + 0] = a.x;
            wt[kk][4 * g + 1] = a.y;
            wt[kk][4 * g + 2] = a.z;
            wt[kk][4 * g + 3] = a.w;
        }
        __syncthreads();
        for (int kk = 0; kk < 32; ++kk) {
            float4 xa = *(float4*)&zT[kk][4 * tr];
            float4 wb = *(float4*)&wt[kk][4 * tc];
            float xav[4] = {xa.x, xa.y, xa.z, xa.w};
            float wbv[4] = {wb.x, wb.y, wb.z, wb.w};
#pragma unroll
            for (int i = 0; i < 4; ++i)
#pragma unroll
                for (int j = 0; j < 4; ++j)
                    acc[i][j] = fmaf(xav[i], wbv[j], acc[i][j]);
        }
    }
    for (int i = 0; i < 4; ++i) {
        int r = r0 + 4 * tr + i;
        float4 s;
        s.x = acc[i][0]; s.y = acc[i][1];
        s.z = acc[i][2]; s.w = acc[i][3];
        *(float4*)&out[(size_t)r * 512 + c0 + 4 * tc] = s;
    }
}

// ---------------------------------------------------------------- launch
extern "C" void kernel_launch(void* const* d_in, const int* in_sizes, int n_in,
                              void* d_out, int out_size, void* d_ws, size_t ws_size,
                              hipStream_t stream) {
    const float* xs   = (const float*)d_in[0];
    const int*   mask = (const int*)d_in[1];
    const float* Wq   = (const float*)d_in[2];
    const float* Wk   = (const float*)d_in[3];
    const float* Wv   = (const float*)d_in[4];
    const float* Wpos = (const float*)d_in[5];
    const float* Wout = (const float*)d_in[6];
    const float* ub   = (const float*)d_in[7];
    const float* vb   = (const float*)d_in[8];
    float* out = (float*)d_out;

    // workspace layout (bf16 elements), total 22.0M elems = 44 MB
    u16* Qu  = (u16*)d_ws;                   // 4194304
    u16* Qv  = Qu + 4194304;
    u16* Kb  = Qv + 4194304;
    u16* Vtg = Kb + 4194304;                 // transposed V (b,h,d,t)
    u16* P   = Vtg + 4194304;                // 8*2047*64 (pad to 1048576)
    u16* Z   = P + 1048576;

    pos_kernel<<<256, 256, 0, stream>>>(Wpos, P);
    qkv_kernel<<<dim3(128, 8), 256, 0, stream>>>(xs, Wq, Wk, Wv, ub, vb, Qu, Qv, Kb, Vtg);
    attn_mfma<<<1024, 256, 0, stream>>>(Qu, Qv, Kb, Vtg, P, mask, Z);
    out_kernel<<<dim3(128, 8), 256, 0, stream>>>(Z, Wout, out);
}

// Round 4
// 304.491 us; speedup vs baseline: 3.7878x; 1.5701x over previous
//
#include <hip/hip_runtime.h>
#include <hip/hip_bf16.h>

// Transformer-XL relative MHA. fp32 in/out, bf16 intermediates in d_ws.
// B=8 T=1024 D_MODEL=512 H=8 DH=64.
// R4: all GEMMs on bf16 MFMA. castX/castW prepare bf16 operands; qkv_mfma
// writes Qb (biasless), Kb, Vt; attn adds u/v bias during Q-frag load.
// Rel-shift identity: bd[t,s] = q_v[t] . p[1023 - t + s].

typedef unsigned short u16;
typedef __attribute__((ext_vector_type(8))) short bf16x8;
typedef __attribute__((ext_vector_type(8))) unsigned short ushort8v;
typedef __attribute__((ext_vector_type(4))) float floatx4;

__device__ __forceinline__ float b2f(u16 u) {
    union { unsigned int i; float f; } x; x.i = ((unsigned int)u) << 16; return x.f;
}
__device__ __forceinline__ u16 f2b(float f) {
    __hip_bfloat16 h = __float2bfloat16(f);
    return *reinterpret_cast<u16*>(&h);
}

#define MFMA16(a, b, c) __builtin_amdgcn_mfma_f32_16x16x32_bf16(a, b, c, 0, 0, 0)

// ---------------------------------------------------------------- casts
__global__ __launch_bounds__(256) void castX(const float* __restrict__ X,
                                             u16* __restrict__ Xb) {
    size_t i = ((size_t)blockIdx.x * 256 + threadIdx.x) * 8;
    float4 a = *(const float4*)&X[i];
    float4 b = *(const float4*)&X[i + 4];
    ushort8v s;
    s[0] = f2b(a.x); s[1] = f2b(a.y); s[2] = f2b(a.z); s[3] = f2b(a.w);
    s[4] = f2b(b.x); s[5] = f2b(b.y); s[6] = f2b(b.z); s[7] = f2b(b.w);
    *(ushort8v*)&Xb[i] = s;
}

// transpose 512x512 fp32 -> bf16 [n][k]; z selects matrix
__global__ __launch_bounds__(256) void castW(
    const float* __restrict__ W0, const float* __restrict__ W1,
    const float* __restrict__ W2, const float* __restrict__ W3,
    u16* __restrict__ WT) {
    __shared__ float t[64][68];
    const float* src = (blockIdx.z == 0) ? W0 : (blockIdx.z == 1) ? W1
                     : (blockIdx.z == 2) ? W2 : W3;
    u16* dst = WT + (size_t)blockIdx.z * 262144;
    const int k0 = blockIdx.x * 64, n0 = blockIdx.y * 64;
    const int tid = threadIdx.x;
    const int r = tid >> 4, c = tid & 15;
#pragma unroll
    for (int rr = 0; rr < 64; rr += 16) {
        float4 v = *(const float4*)&src[(size_t)(k0 + r + rr) * 512 + n0 + 4 * c];
        t[r + rr][4 * c + 0] = v.x;
        t[r + rr][4 * c + 1] = v.y;
        t[r + rr][4 * c + 2] = v.z;
        t[r + rr][4 * c + 3] = v.w;
    }
    __syncthreads();
    const int nrow = tid >> 2, kc = (tid & 3) * 16;
    ushort8v s0, s1;
#pragma unroll
    for (int e = 0; e < 8; ++e) {
        s0[e] = f2b(t[kc + e][nrow]);
        s1[e] = f2b(t[kc + 8 + e][nrow]);
    }
    *(ushort8v*)&dst[(size_t)(n0 + nrow) * 512 + k0 + kc] = s0;
    *(ushort8v*)&dst[(size_t)(n0 + nrow) * 512 + k0 + kc + 8] = s1;
}

// ---------------------------------------------------------------- pos kernel
__global__ __launch_bounds__(256) void pos_kernel(const float* __restrict__ Wpos,
                                                  u16* __restrict__ P) {
    __shared__ float pe[8][512];
    const int tid = threadIdx.x;
    const int l0 = blockIdx.x * 8;
    float invf = expf(-9.210340371976184f * ((float)tid / 256.0f));
    for (int il = 0; il < 8; ++il) {
        int l = l0 + il; if (l > 2046) l = 2046;
        float ang = (float)(l - 1023) * invf;
        pe[il][2 * tid]     = sinf(ang);
        pe[il][2 * tid + 1] = cosf(ang);
    }
    __syncthreads();
    float acc[8][2];
    for (int il = 0; il < 8; ++il) { acc[il][0] = 0.f; acc[il][1] = 0.f; }
    for (int k = 0; k < 512; ++k) {
        float w0 = Wpos[k * 512 + tid];
        float w1 = Wpos[k * 512 + tid + 256];
#pragma unroll
        for (int il = 0; il < 8; ++il) {
            float pk = pe[il][k];
            acc[il][0] = fmaf(pk, w0, acc[il][0]);
            acc[il][1] = fmaf(pk, w1, acc[il][1]);
        }
    }
    for (int il = 0; il < 8; ++il) {
        int l = l0 + il; if (l >= 2047) break;
        int c0 = tid, c1 = tid + 256;
        P[((size_t)(c0 >> 6) * 2047 + l) * 64 + (c0 & 63)] = f2b(acc[il][0]);
        P[((size_t)(c1 >> 6) * 2047 + l) * 64 + (c1 & 63)] = f2b(acc[il][1]);
    }
}

// ---------------------------------------------------------------- qkv MFMA
// grid (64, 12): x -> 128 rows of xs; y: 0-3 Q, 4-7 K, 8-11 V (n0=(y&3)*128).
// Q/K: D^T (A=W rows -> frag regs consecutive d). V: D (regs consecutive t).
__global__ __launch_bounds__(256, 2) void qkv_mfma(
    const u16* __restrict__ Xb, const u16* __restrict__ WqT,
    const u16* __restrict__ WkT, const u16* __restrict__ WvT,
    u16* __restrict__ Qb, u16* __restrict__ Kb, u16* __restrict__ Vtg)
{
    __shared__ u16 Xl[128 * 40];
    __shared__ u16 Wl[128 * 40];
    const int tid = threadIdx.x;
    const int lane = tid & 63, w = tid >> 6;
    const int quad = lane >> 4, ln = lane & 15;
    const int wm = w & 1, wn = w >> 1;

    const int m0 = blockIdx.x * 128;
    const int sel = blockIdx.y >> 2;
    const int n0 = (blockIdx.y & 3) * 128;
    const u16* WT = (sel == 0) ? WqT : (sel == 1) ? WkT : WvT;
    const int b = m0 >> 10, tbase = m0 & 1023;

    floatx4 acc[4][4];
#pragma unroll
    for (int i = 0; i < 4; ++i)
#pragma unroll
        for (int j = 0; j < 4; ++j) acc[i][j] = (floatx4){0.f, 0.f, 0.f, 0.f};

    for (int kc = 0; kc < 512; kc += 32) {
        __syncthreads();
#pragma unroll
        for (int it = 0; it < 2; ++it) {
            int idx = tid + (it << 8);
            int r = idx >> 2, g = idx & 3;
            *(ushort8v*)&Xl[r * 40 + g * 8] =
                *(const ushort8v*)&Xb[(size_t)(m0 + r) * 512 + kc + g * 8];
            *(ushort8v*)&Wl[r * 40 + g * 8] =
                *(const ushort8v*)&WT[(size_t)(n0 + r) * 512 + kc + g * 8];
        }
        __syncthreads();
        bf16x8 am[4], an[4];
#pragma unroll
        for (int i = 0; i < 4; ++i)
            am[i] = *(bf16x8*)&Xl[(wm * 64 + i * 16 + ln) * 40 + quad * 8];
#pragma unroll
        for (int j = 0; j < 4; ++j)
            an[j] = *(bf16x8*)&Wl[(wn * 64 + j * 16 + ln) * 40 + quad * 8];
        if (sel < 2) {
#pragma unroll
            for (int i = 0; i < 4; ++i)
#pragma unroll
                for (int j = 0; j < 4; ++j)
                    acc[i][j] = MFMA16(an[j], am[i], acc[i][j]);
        } else {
#pragma unroll
            for (int i = 0; i < 4; ++i)
#pragma unroll
                for (int j = 0; j < 4; ++j)
                    acc[i][j] = MFMA16(am[i], an[j], acc[i][j]);
        }
    }
    if (sel < 2) {
        u16* dst = (sel == 0) ? Qb : Kb;
#pragma unroll
        for (int i = 0; i < 4; ++i) {
            int t = tbase + wm * 64 + i * 16 + ln;
#pragma unroll
            for (int j = 0; j < 4; ++j) {
                int n = n0 + wn * 64 + j * 16 + quad * 4;
                int h = n >> 6, d = n & 63;
                ushort4 s;
                s.x = f2b(acc[i][j][0]); s.y = f2b(acc[i][j][1]);
                s.z = f2b(acc[i][j][2]); s.w = f2b(acc[i][j][3]);
                *(ushort4*)&dst[(((size_t)b * 8 + h) * 1024 + t) * 64 + d] = s;
            }
        }
    } else {
#pragma unroll
        for (int i = 0; i < 4; ++i) {
            int t4 = tbase + wm * 64 + i * 16 + quad * 4;
#pragma unroll
            for (int j = 0; j < 4; ++j) {
                int n = n0 + wn * 64 + j * 16 + ln;
                int h = n >> 6, d = n & 63;
                ushort4 s;
                s.x = f2b(acc[i][j][0]); s.y = f2b(acc[i][j][1]);
                s.z = f2b(acc[i][j][2]); s.w = f2b(acc[i][j][3]);
                *(ushort4*)&Vtg[(((size_t)b * 8 + h) * 64 + d) * 1024 + t4] = s;
            }
        }
    }
}

// ---------------------------------------------------------------- attention
__device__ __forceinline__ bf16x8 addbias(bf16x8 q, const float* __restrict__ bias) {
    float4 a = *(const float4*)&bias[0];
    float4 b = *(const float4*)&bias[4];
    bf16x8 r;
    r[0] = (short)f2b(b2f((u16)q[0]) + a.x);
    r[1] = (short)f2b(b2f((u16)q[1]) + a.y);
    r[2] = (short)f2b(b2f((u16)q[2]) + a.z);
    r[3] = (short)f2b(b2f((u16)q[3]) + a.w);
    r[4] = (short)f2b(b2f((u16)q[4]) + b.x);
    r[5] = (short)f2b(b2f((u16)q[5]) + b.y);
    r[6] = (short)f2b(b2f((u16)q[6]) + b.z);
    r[7] = (short)f2b(b2f((u16)q[7]) + b.w);
    return r;
}

// Block = (b, h, 64 q-rows) = 4 waves x 16 rows. S-chunks of 64.
__global__ __launch_bounds__(256, 2) void attn_mfma(
    const u16* __restrict__ Qb,
    const u16* __restrict__ Kb, const u16* __restrict__ Vtg,
    const u16* __restrict__ P, const int* __restrict__ mask,
    const float* __restrict__ ub, const float* __restrict__ vb,
    u16* __restrict__ Z)
{
    __shared__ u16 Klds[64 * 72];          // [s][d] stride 72
    __shared__ u16 Vtlds[64 * 72];         // [d][s] stride 72
    __shared__ u16 Pb[128 * 64];           // [j][d] XOR-swizzled 16B blocks
    __shared__ unsigned long long Mrow[64];
    __shared__ float Gl[4][16 * 80];       // per wave: [tt][j] stride 80
    __shared__ u16 Prob[4][16 * 72];       // per wave: [tt][ss] stride 72

    const int tid  = threadIdx.x;
    const int lane = tid & 63;
    const int w    = tid >> 6;
    const int quad = lane >> 4;
    const int ln   = lane & 15;

    const int bid = blockIdx.x;
    const int t0 = (bid & 15) << 6;
    const int h  = (bid >> 4) & 7;
    const int b  = bid >> 7;
    const size_t bh  = ((size_t)b * 8 + h) * 1024;
    const size_t bhd = ((size_t)b * 8 + h) * 64;

    // register B-fragments with bias add (once per block)
    const size_t qoff = (bh + t0 + 16 * w + ln) * 64;
    const bf16x8 q0 = *(const bf16x8*)&Qb[qoff + quad * 8];
    const bf16x8 q1 = *(const bf16x8*)&Qb[qoff + 32 + quad * 8];
    const bf16x8 qu0 = addbias(q0, &ub[h * 64 + quad * 8]);
    const bf16x8 qu1 = addbias(q1, &ub[h * 64 + 32 + quad * 8]);
    const bf16x8 qv0 = addbias(q0, &vb[h * 64 + quad * 8]);
    const bf16x8 qv1 = addbias(q1, &vb[h * 64 + 32 + quad * 8]);

    floatx4 O0 = {0.f, 0.f, 0.f, 0.f}, O1 = O0, O2 = O0, O3 = O0;
    float m_run = -3.0e38f, l_run = 0.f;

    for (int s0 = 0; s0 < 1024; s0 += 64) {
        __syncthreads();
#pragma unroll
        for (int it = 0; it < 2; ++it) {
            int idx = tid + (it << 8);
            int r = idx >> 3, g = idx & 7;
            *(ushort8v*)&Klds[r * 72 + g * 8] =
                *(const ushort8v*)&Kb[(bh + s0 + r) * 64 + g * 8];
            *(ushort8v*)&Vtlds[r * 72 + g * 8] =
                *(const ushort8v*)&Vtg[(bhd + r) * 1024 + s0 + g * 8];
        }
        const int lb0 = 960 - t0 + s0;
#pragma unroll
        for (int it = 0; it < 4; ++it) {
            int idx = tid + (it << 8);
            int r = idx >> 3, g = idx & 7;
            int l = lb0 + r; if (l > 2046) l = 2046;
            *(ushort8v*)&Pb[r * 64 + (((g ^ (r & 7))) << 3)] =
                *(const ushort8v*)&P[((size_t)h * 2047 + l) * 64 + g * 8];
        }
        {
            int mv[16];
#pragma unroll
            for (int rr = 0; rr < 16; ++rr)
                mv[rr] = mask[((size_t)b * 1024 + t0 + 16 * w + rr) * 1024 + s0 + lane];
#pragma unroll
            for (int rr = 0; rr < 16; ++rr) {
                unsigned long long bits = __ballot(mv[rr] != 0);
                if (lane == 0) Mrow[16 * w + rr] = bits;
            }
        }
        __syncthreads();

        // BD: G^T[j][tt] = Pband . Qv^T  (j = ss - tt + 15)
        float* gw = &Gl[w][0];
#pragma unroll
        for (int jt = 0; jt < 5; ++jt) {
            int jr = 48 - 16 * w + jt * 16 + ln;
            floatx4 g = {0.f, 0.f, 0.f, 0.f};
            bf16x8 a0 = *(bf16x8*)&Pb[jr * 64 + ((quad ^ (jr & 7)) << 3)];
            bf16x8 a1 = *(bf16x8*)&Pb[jr * 64 + (((4 + quad) ^ (jr & 7)) << 3)];
            g = MFMA16(a0, qv0, g);
            g = MFMA16(a1, qv1, g);
            *(floatx4*)&gw[ln * 80 + jt * 16 + quad * 4] = g;
        }
        // AC: S^T[ss][tt] = K . Qu^T
        floatx4 cac[4];
#pragma unroll
        for (int st = 0; st < 4; ++st) {
            floatx4 c = {0.f, 0.f, 0.f, 0.f};
            int kr = st * 16 + ln;
            bf16x8 a0 = *(bf16x8*)&Klds[kr * 72 + quad * 8];
            bf16x8 a1 = *(bf16x8*)&Klds[kr * 72 + 32 + quad * 8];
            c = MFMA16(a0, qu0, c);
            c = MFMA16(a1, qu1, c);
            cac[st] = c;
        }
        // scores + online softmax (lane owns col tt = ln)
        const unsigned long long bits = Mrow[16 * w + ln];
        float sc[4][4];
        float cmax = -3.0e38f;
#pragma unroll
        for (int st = 0; st < 4; ++st) {
            int j0 = st * 16 + quad * 4 + 15 - ln;
#pragma unroll
            for (int r = 0; r < 4; ++r) {
                float v = (cac[st][r] + gw[ln * 80 + j0 + r]) * 0.125f;
                int ss = st * 16 + quad * 4 + r;
                v = ((bits >> ss) & 1ull) ? v : -1.0e30f;
                sc[st][r] = v;
                cmax = fmaxf(cmax, v);
            }
        }
        cmax = fmaxf(cmax, __shfl_xor(cmax, 16));
        cmax = fmaxf(cmax, __shfl_xor(cmax, 32));
        float m_new = fmaxf(m_run, cmax);
        float alpha = __expf(m_run - m_new);
        float psum = 0.f;
#pragma unroll
        for (int st = 0; st < 4; ++st) {
            float p0 = __expf(sc[st][0] - m_new);
            float p1 = __expf(sc[st][1] - m_new);
            float p2 = __expf(sc[st][2] - m_new);
            float p3 = __expf(sc[st][3] - m_new);
            psum += (p0 + p1) + (p2 + p3);
            ushort4 pk;
            pk.x = f2b(p0); pk.y = f2b(p1); pk.z = f2b(p2); pk.w = f2b(p3);
            *(ushort4*)&Prob[w][ln * 72 + st * 16 + quad * 4] = pk;
        }
        psum += __shfl_xor(psum, 16);
        psum += __shfl_xor(psum, 32);
        l_run = l_run * alpha + psum;
        m_run = m_new;
        float a0s = __shfl(alpha, quad * 4 + 0);
        float a1s = __shfl(alpha, quad * 4 + 1);
        float a2s = __shfl(alpha, quad * 4 + 2);
        float a3s = __shfl(alpha, quad * 4 + 3);
        O0[0] *= a0s; O0[1] *= a1s; O0[2] *= a2s; O0[3] *= a3s;
        O1[0] *= a0s; O1[1] *= a1s; O1[2] *= a2s; O1[3] *= a3s;
        O2[0] *= a0s; O2[1] *= a1s; O2[2] *= a2s; O2[3] *= a3s;
        O3[0] *= a0s; O3[1] *= a1s; O3[2] *= a2s; O3[3] *= a3s;
        // PV
        bf16x8 pa0 = *(bf16x8*)&Prob[w][ln * 72 + quad * 8];
        bf16x8 pa1 = *(bf16x8*)&Prob[w][ln * 72 + 32 + quad * 8];
        {
            bf16x8 v0 = *(bf16x8*)&Vtlds[(0 + ln) * 72 + quad * 8];
            bf16x8 v1 = *(bf16x8*)&Vtlds[(0 + ln) * 72 + 32 + quad * 8];
            O0 = MFMA16(pa0, v0, O0); O0 = MFMA16(pa1, v1, O0);
        }
        {
            bf16x8 v0 = *(bf16x8*)&Vtlds[(16 + ln) * 72 + quad * 8];
            bf16x8 v1 = *(bf16x8*)&Vtlds[(16 + ln) * 72 + 32 + quad * 8];
            O1 = MFMA16(pa0, v0, O1); O1 = MFMA16(pa1, v1, O1);
        }
        {
            bf16x8 v0 = *(bf16x8*)&Vtlds[(32 + ln) * 72 + quad * 8];
            bf16x8 v1 = *(bf16x8*)&Vtlds[(32 + ln) * 72 + 32 + quad * 8];
            O2 = MFMA16(pa0, v0, O2); O2 = MFMA16(pa1, v1, O2);
        }
        {
            bf16x8 v0 = *(bf16x8*)&Vtlds[(48 + ln) * 72 + quad * 8];
            bf16x8 v1 = *(bf16x8*)&Vtlds[(48 + ln) * 72 + 32 + quad * 8];
            O3 = MFMA16(pa0, v0, O3); O3 = MFMA16(pa1, v1, O3);
        }
    }
    float li0 = 1.0f / __shfl(l_run, quad * 4 + 0);
    float li1 = 1.0f / __shfl(l_run, quad * 4 + 1);
    float li2 = 1.0f / __shfl(l_run, quad * 4 + 2);
    float li3 = 1.0f / __shfl(l_run, quad * 4 + 3);
    float li[4] = {li0, li1, li2, li3};
#pragma unroll
    for (int r = 0; r < 4; ++r) {
        size_t zo = ((size_t)b * 1024 + t0 + 16 * w + quad * 4 + r) * 512 + h * 64 + ln;
        Z[zo + 0]  = f2b(O0[r] * li[r]);
        Z[zo + 16] = f2b(O1[r] * li[r]);
        Z[zo + 32] = f2b(O2[r] * li[r]);
        Z[zo + 48] = f2b(O3[r] * li[r]);
    }
}

// ---------------------------------------------------------------- out MFMA
// grid (64, 4). D^T: rows n (regs = 4 consecutive n) -> float4 stores.
__global__ __launch_bounds__(256, 2) void out_mfma(
    const u16* __restrict__ Zb, const u16* __restrict__ WoT,
    float* __restrict__ out)
{
    __shared__ u16 Xl[128 * 40];
    __shared__ u16 Wl[128 * 40];
    const int tid = threadIdx.x;
    const int lane = tid & 63, w = tid >> 6;
    const int quad = lane >> 4, ln = lane & 15;
    const int wm = w & 1, wn = w >> 1;
    const int m0 = blockIdx.x * 128;
    const int n0 = blockIdx.y * 128;

    floatx4 acc[4][4];
#pragma unroll
    for (int i = 0; i < 4; ++i)
#pragma unroll
        for (int j = 0; j < 4; ++j) acc[i][j] = (floatx4){0.f, 0.f, 0.f, 0.f};

    for (int kc = 0; kc < 512; kc += 32) {
        __syncthreads();
#pragma unroll
        for (int it = 0; it < 2; ++it) {
            int idx = tid + (it << 8);
            int r = idx >> 2, g = idx & 3;
            *(ushort8v*)&Xl[r * 40 + g * 8] =
                *(const ushort8v*)&Zb[(size_t)(m0 + r) * 512 + kc + g * 8];
            *(ushort8v*)&Wl[r * 40 + g * 8] =
                *(const ushort8v*)&WoT[(size_t)(n0 + r) * 512 + kc + g * 8];
        }
        __syncthreads();
        bf16x8 am[4], an[4];
#pragma unroll
        for (int i = 0; i < 4; ++i)
            am[i] = *(bf16x8*)&Xl[(wm * 64 + i * 16 + ln) * 40 + quad * 8];
#pragma unroll
        for (int j = 0; j < 4; ++j)
            an[j] = *(bf16x8*)&Wl[(wn * 64 + j * 16 + ln) * 40 + quad * 8];
#pragma unroll
        for (int i = 0; i < 4; ++i)
#pragma unroll
            for (int j = 0; j < 4; ++j)
                acc[i][j] = MFMA16(an[j], am[i], acc[i][j]);
    }
#pragma unroll
    for (int i = 0; i < 4; ++i) {
        int m = m0 + wm * 64 + i * 16 + ln;
#pragma unroll
        for (int j = 0; j < 4; ++j) {
            int n = n0 + wn * 64 + j * 16 + quad * 4;
            float4 s;
            s.x = acc[i][j][0]; s.y = acc[i][j][1];
            s.z = acc[i][j][2]; s.w = acc[i][j][3];
            *(float4*)&out[(size_t)m * 512 + n] = s;
        }
    }
}

// ---------------------------------------------------------------- launch
extern "C" void kernel_launch(void* const* d_in, const int* in_sizes, int n_in,
                              void* d_out, int out_size, void* d_ws, size_t ws_size,
                              hipStream_t stream) {
    const float* xs   = (const float*)d_in[0];
    const int*   mask = (const int*)d_in[1];
    const float* Wq   = (const float*)d_in[2];
    const float* Wk   = (const float*)d_in[3];
    const float* Wv   = (const float*)d_in[4];
    const float* Wpos = (const float*)d_in[5];
    const float* Wout = (const float*)d_in[6];
    const float* ub   = (const float*)d_in[7];
    const float* vb   = (const float*)d_in[8];
    float* out = (float*)d_out;

    // workspace (bf16 elems), total 18874368 elems = 37.75 MB
    u16* Qb  = (u16*)d_ws;                   // 4194304
    u16* Kb  = Qb + 4194304;                 // 4194304
    u16* Vtg = Kb + 4194304;                 // 4194304
    u16* P   = Vtg + 4194304;                // 1048576
    u16* XZ  = P + 1048576;                  // 4194304 (Xb, then reused as Z)
    u16* WT  = XZ + 4194304;                 // 4*262144
    u16* WqT = WT;
    u16* WkT = WT + 262144;
    u16* WvT = WT + 524288;
    u16* WoT = WT + 786432;

    castX<<<2048, 256, 0, stream>>>(xs, XZ);
    castW<<<dim3(8, 8, 4), 256, 0, stream>>>(Wq, Wk, Wv, Wout, WT);
    pos_kernel<<<256, 256, 0, stream>>>(Wpos, P);
    qkv_mfma<<<dim3(64, 12), 256, 0, stream>>>(XZ, WqT, WkT, WvT, Qb, Kb, Vtg);
    attn_mfma<<<1024, 256, 0, stream>>>(Qb, Kb, Vtg, P, mask, ub, vb, XZ);
    out_mfma<<<dim3(64, 4), 256, 0, stream>>>(XZ, WoT, out);
}

// Round 5
// 293.923 us; speedup vs baseline: 3.9240x; 1.0360x over previous
//
#include <hip/hip_runtime.h>
#include <hip/hip_bf16.h>

// Transformer-XL relative MHA. fp32 in/out, bf16 intermediates in d_ws.
// B=8 T=1024 D_MODEL=512 H=8 DH=64.
// R5: mask pre-packed to u64 ballots (Mp) once in prep_kernel (fused with
// castX/castW); attn loses 4096 loads + 64 ballots per block-chunk.
// Rel-shift identity: bd[t,s] = q_v[t] . p[1023 - t + s].

typedef unsigned short u16;
typedef unsigned long long u64;
typedef __attribute__((ext_vector_type(8))) short bf16x8;
typedef __attribute__((ext_vector_type(8))) unsigned short ushort8v;
typedef __attribute__((ext_vector_type(4))) float floatx4;

__device__ __forceinline__ float b2f(u16 u) {
    union { unsigned int i; float f; } x; x.i = ((unsigned int)u) << 16; return x.f;
}
__device__ __forceinline__ u16 f2b(float f) {
    __hip_bfloat16 h = __float2bfloat16(f);
    return *reinterpret_cast<u16*>(&h);
}

#define MFMA16(a, b, c) __builtin_amdgcn_mfma_f32_16x16x32_bf16(a, b, c, 0, 0, 0)

// ---------------------------------------------------------------- prep
// blocks [0,2048): castX ; [2048,2304): castW (4 matrices) ; [2304,4352): maskpack
__global__ __launch_bounds__(256) void prep_kernel(
    const float* __restrict__ X, u16* __restrict__ Xb,
    const float* __restrict__ W0, const float* __restrict__ W1,
    const float* __restrict__ W2, const float* __restrict__ W3,
    u16* __restrict__ WT,
    const int* __restrict__ mask, u64* __restrict__ Mp)
{
    const int bi = blockIdx.x;
    const int tid = threadIdx.x;
    if (bi < 2048) {
        // ---- castX: xs fp32 -> bf16
        size_t i = ((size_t)bi * 256 + tid) * 8;
        float4 a = *(const float4*)&X[i];
        float4 b = *(const float4*)&X[i + 4];
        ushort8v s;
        s[0] = f2b(a.x); s[1] = f2b(a.y); s[2] = f2b(a.z); s[3] = f2b(a.w);
        s[4] = f2b(b.x); s[5] = f2b(b.y); s[6] = f2b(b.z); s[7] = f2b(b.w);
        *(ushort8v*)&Xb[i] = s;
    } else if (bi < 2304) {
        // ---- castW: transpose 512x512 fp32 -> bf16 [n][k]
        __shared__ float t[64][68];
        const int li = bi - 2048;
        const int m = li >> 6;
        const float* src = (m == 0) ? W0 : (m == 1) ? W1 : (m == 2) ? W2 : W3;
        u16* dst = WT + (size_t)m * 262144;
        const int k0 = ((li >> 3) & 7) * 64, n0 = (li & 7) * 64;
        const int r = tid >> 4, c = tid & 15;
#pragma unroll
        for (int rr = 0; rr < 64; rr += 16) {
            float4 v = *(const float4*)&src[(size_t)(k0 + r + rr) * 512 + n0 + 4 * c];
            t[r + rr][4 * c + 0] = v.x;
            t[r + rr][4 * c + 1] = v.y;
            t[r + rr][4 * c + 2] = v.z;
            t[r + rr][4 * c + 3] = v.w;
        }
        __syncthreads();
        const int nrow = tid >> 2, kc = (tid & 3) * 16;
        ushort8v s0, s1;
#pragma unroll
        for (int e = 0; e < 8; ++e) {
            s0[e] = f2b(t[kc + e][nrow]);
            s1[e] = f2b(t[kc + 8 + e][nrow]);
        }
        *(ushort8v*)&dst[(size_t)(n0 + nrow) * 512 + k0 + kc] = s0;
        *(ushort8v*)&dst[(size_t)(n0 + nrow) * 512 + k0 + kc + 8] = s1;
    } else {
        // ---- maskpack: one wave per row; Mp[row][w] = ballot(mask[row][64w+lane])
        const int lane = tid & 63, w = tid >> 6;
        const int row = (bi - 2304) * 4 + w;   // 0..8191  (b*1024+t)
#pragma unroll
        for (int j = 0; j < 16; ++j) {
            int v = mask[(size_t)row * 1024 + j * 64 + lane];
            u64 bits = __ballot(v != 0);
            if (lane == j) Mp[(size_t)row * 16 + j] = bits;
        }
    }
}

// ---------------------------------------------------------------- pos kernel
__global__ __launch_bounds__(256) void pos_kernel(const float* __restrict__ Wpos,
                                                  u16* __restrict__ P) {
    __shared__ float pe[8][512];
    const int tid = threadIdx.x;
    const int l0 = blockIdx.x * 8;
    float invf = expf(-9.210340371976184f * ((float)tid / 256.0f));
    for (int il = 0; il < 8; ++il) {
        int l = l0 + il; if (l > 2046) l = 2046;
        float ang = (float)(l - 1023) * invf;
        pe[il][2 * tid]     = sinf(ang);
        pe[il][2 * tid + 1] = cosf(ang);
    }
    __syncthreads();
    float acc[8][2];
    for (int il = 0; il < 8; ++il) { acc[il][0] = 0.f; acc[il][1] = 0.f; }
    for (int k = 0; k < 512; ++k) {
        float w0 = Wpos[k * 512 + tid];
        float w1 = Wpos[k * 512 + tid + 256];
#pragma unroll
        for (int il = 0; il < 8; ++il) {
            float pk = pe[il][k];
            acc[il][0] = fmaf(pk, w0, acc[il][0]);
            acc[il][1] = fmaf(pk, w1, acc[il][1]);
        }
    }
    for (int il = 0; il < 8; ++il) {
        int l = l0 + il; if (l >= 2047) break;
        int c0 = tid, c1 = tid + 256;
        P[((size_t)(c0 >> 6) * 2047 + l) * 64 + (c0 & 63)] = f2b(acc[il][0]);
        P[((size_t)(c1 >> 6) * 2047 + l) * 64 + (c1 & 63)] = f2b(acc[il][1]);
    }
}

// ---------------------------------------------------------------- qkv MFMA
// grid (64, 12): x -> 128 rows of xs; y: 0-3 Q, 4-7 K, 8-11 V (n0=(y&3)*128).
__global__ __launch_bounds__(256, 2) void qkv_mfma(
    const u16* __restrict__ Xb, const u16* __restrict__ WqT,
    const u16* __restrict__ WkT, const u16* __restrict__ WvT,
    u16* __restrict__ Qb, u16* __restrict__ Kb, u16* __restrict__ Vtg)
{
    __shared__ u16 Xl[128 * 40];
    __shared__ u16 Wl[128 * 40];
    const int tid = threadIdx.x;
    const int lane = tid & 63, w = tid >> 6;
    const int quad = lane >> 4, ln = lane & 15;
    const int wm = w & 1, wn = w >> 1;

    const int m0 = blockIdx.x * 128;
    const int sel = blockIdx.y >> 2;
    const int n0 = (blockIdx.y & 3) * 128;
    const u16* WT = (sel == 0) ? WqT : (sel == 1) ? WkT : WvT;
    const int b = m0 >> 10, tbase = m0 & 1023;

    floatx4 acc[4][4];
#pragma unroll
    for (int i = 0; i < 4; ++i)
#pragma unroll
        for (int j = 0; j < 4; ++j) acc[i][j] = (floatx4){0.f, 0.f, 0.f, 0.f};

    for (int kc = 0; kc < 512; kc += 32) {
        __syncthreads();
#pragma unroll
        for (int it = 0; it < 2; ++it) {
            int idx = tid + (it << 8);
            int r = idx >> 2, g = idx & 3;
            *(ushort8v*)&Xl[r * 40 + g * 8] =
                *(const ushort8v*)&Xb[(size_t)(m0 + r) * 512 + kc + g * 8];
            *(ushort8v*)&Wl[r * 40 + g * 8] =
                *(const ushort8v*)&WT[(size_t)(n0 + r) * 512 + kc + g * 8];
        }
        __syncthreads();
        bf16x8 am[4], an[4];
#pragma unroll
        for (int i = 0; i < 4; ++i)
            am[i] = *(bf16x8*)&Xl[(wm * 64 + i * 16 + ln) * 40 + quad * 8];
#pragma unroll
        for (int j = 0; j < 4; ++j)
            an[j] = *(bf16x8*)&Wl[(wn * 64 + j * 16 + ln) * 40 + quad * 8];
        if (sel < 2) {
#pragma unroll
            for (int i = 0; i < 4; ++i)
#pragma unroll
                for (int j = 0; j < 4; ++j)
                    acc[i][j] = MFMA16(an[j], am[i], acc[i][j]);
        } else {
#pragma unroll
            for (int i = 0; i < 4; ++i)
#pragma unroll
                for (int j = 0; j < 4; ++j)
                    acc[i][j] = MFMA16(am[i], an[j], acc[i][j]);
        }
    }
    if (sel < 2) {
        u16* dst = (sel == 0) ? Qb : Kb;
#pragma unroll
        for (int i = 0; i < 4; ++i) {
            int t = tbase + wm * 64 + i * 16 + ln;
#pragma unroll
            for (int j = 0; j < 4; ++j) {
                int n = n0 + wn * 64 + j * 16 + quad * 4;
                int h = n >> 6, d = n & 63;
                ushort4 s;
                s.x = f2b(acc[i][j][0]); s.y = f2b(acc[i][j][1]);
                s.z = f2b(acc[i][j][2]); s.w = f2b(acc[i][j][3]);
                *(ushort4*)&dst[(((size_t)b * 8 + h) * 1024 + t) * 64 + d] = s;
            }
        }
    } else {
#pragma unroll
        for (int i = 0; i < 4; ++i) {
            int t4 = tbase + wm * 64 + i * 16 + quad * 4;
#pragma unroll
            for (int j = 0; j < 4; ++j) {
                int n = n0 + wn * 64 + j * 16 + ln;
                int h = n >> 6, d = n & 63;
                ushort4 s;
                s.x = f2b(acc[i][j][0]); s.y = f2b(acc[i][j][1]);
                s.z = f2b(acc[i][j][2]); s.w = f2b(acc[i][j][3]);
                *(ushort4*)&Vtg[(((size_t)b * 8 + h) * 64 + d) * 1024 + t4] = s;
            }
        }
    }
}

// ---------------------------------------------------------------- attention
__device__ __forceinline__ bf16x8 addbias(bf16x8 q, const float* __restrict__ bias) {
    float4 a = *(const float4*)&bias[0];
    float4 b = *(const float4*)&bias[4];
    bf16x8 r;
    r[0] = (short)f2b(b2f((u16)q[0]) + a.x);
    r[1] = (short)f2b(b2f((u16)q[1]) + a.y);
    r[2] = (short)f2b(b2f((u16)q[2]) + a.z);
    r[3] = (short)f2b(b2f((u16)q[3]) + a.w);
    r[4] = (short)f2b(b2f((u16)q[4]) + b.x);
    r[5] = (short)f2b(b2f((u16)q[5]) + b.y);
    r[6] = (short)f2b(b2f((u16)q[6]) + b.z);
    r[7] = (short)f2b(b2f((u16)q[7]) + b.w);
    return r;
}

// Block = (b, h, 64 q-rows) = 4 waves x 16 rows. S-chunks of 64.
__global__ __launch_bounds__(256, 2) void attn_mfma(
    const u16* __restrict__ Qb,
    const u16* __restrict__ Kb, const u16* __restrict__ Vtg,
    const u16* __restrict__ P, const u64* __restrict__ Mp,
    const float* __restrict__ ub, const float* __restrict__ vb,
    u16* __restrict__ Z)
{
    __shared__ u16 Klds[64 * 72];          // [s][d] stride 72
    __shared__ u16 Vtlds[64 * 72];         // [d][s] stride 72
    __shared__ u16 Pb[128 * 64];           // [j][d] XOR-swizzled 16B blocks
    __shared__ float Gl[4][16 * 80];       // per wave: [tt][j] stride 80
    __shared__ u16 Prob[4][16 * 72];       // per wave: [tt][ss] stride 72

    const int tid  = threadIdx.x;
    const int lane = tid & 63;
    const int w    = tid >> 6;
    const int quad = lane >> 4;
    const int ln   = lane & 15;

    const int bid = blockIdx.x;
    const int t0 = (bid & 15) << 6;
    const int h  = (bid >> 4) & 7;
    const int b  = bid >> 7;
    const size_t bh  = ((size_t)b * 8 + h) * 1024;
    const size_t bhd = ((size_t)b * 8 + h) * 64;
    // packed-mask row for this lane's tt column (row index = ln within wave tile)
    const size_t mprow = ((size_t)b * 1024 + t0 + 16 * w + ln) * 16;

    // register B-fragments with bias add (once per block)
    const size_t qoff = (bh + t0 + 16 * w + ln) * 64;
    const bf16x8 q0 = *(const bf16x8*)&Qb[qoff + quad * 8];
    const bf16x8 q1 = *(const bf16x8*)&Qb[qoff + 32 + quad * 8];
    const bf16x8 qu0 = addbias(q0, &ub[h * 64 + quad * 8]);
    const bf16x8 qu1 = addbias(q1, &ub[h * 64 + 32 + quad * 8]);
    const bf16x8 qv0 = addbias(q0, &vb[h * 64 + quad * 8]);
    const bf16x8 qv1 = addbias(q1, &vb[h * 64 + 32 + quad * 8]);

    floatx4 O0 = {0.f, 0.f, 0.f, 0.f}, O1 = O0, O2 = O0, O3 = O0;
    float m_run = -3.0e38f, l_run = 0.f;

    for (int s0 = 0; s0 < 1024; s0 += 64) {
        __syncthreads();
#pragma unroll
        for (int it = 0; it < 2; ++it) {
            int idx = tid + (it << 8);
            int r = idx >> 3, g = idx & 7;
            *(ushort8v*)&Klds[r * 72 + g * 8] =
                *(const ushort8v*)&Kb[(bh + s0 + r) * 64 + g * 8];
            *(ushort8v*)&Vtlds[r * 72 + g * 8] =
                *(const ushort8v*)&Vtg[(bhd + r) * 1024 + s0 + g * 8];
        }
        const int lb0 = 960 - t0 + s0;
#pragma unroll
        for (int it = 0; it < 4; ++it) {
            int idx = tid + (it << 8);
            int r = idx >> 3, g = idx & 7;
            int l = lb0 + r; if (l > 2046) l = 2046;
            *(ushort8v*)&Pb[r * 64 + (((g ^ (r & 7))) << 3)] =
                *(const ushort8v*)&P[((size_t)h * 2047 + l) * 64 + g * 8];
        }
        const u64 bits = Mp[mprow + (s0 >> 6)];
        __syncthreads();

        // BD: G^T[j][tt] = Pband . Qv^T  (j = ss - tt + 15)
        float* gw = &Gl[w][0];
#pragma unroll
        for (int jt = 0; jt < 5; ++jt) {
            int jr = 48 - 16 * w + jt * 16 + ln;
            floatx4 g = {0.f, 0.f, 0.f, 0.f};
            bf16x8 a0 = *(bf16x8*)&Pb[jr * 64 + ((quad ^ (jr & 7)) << 3)];
            bf16x8 a1 = *(bf16x8*)&Pb[jr * 64 + (((4 + quad) ^ (jr & 7)) << 3)];
            g = MFMA16(a0, qv0, g);
            g = MFMA16(a1, qv1, g);
            *(floatx4*)&gw[ln * 80 + jt * 16 + quad * 4] = g;
        }
        // AC: S^T[ss][tt] = K . Qu^T
        floatx4 cac[4];
#pragma unroll
        for (int st = 0; st < 4; ++st) {
            floatx4 c = {0.f, 0.f, 0.f, 0.f};
            int kr = st * 16 + ln;
            bf16x8 a0 = *(bf16x8*)&Klds[kr * 72 + quad * 8];
            bf16x8 a1 = *(bf16x8*)&Klds[kr * 72 + 32 + quad * 8];
            c = MFMA16(a0, qu0, c);
            c = MFMA16(a1, qu1, c);
            cac[st] = c;
        }
        // scores + online softmax (lane owns col tt = ln)
        float sc[4][4];
        float cmax = -3.0e38f;
#pragma unroll
        for (int st = 0; st < 4; ++st) {
            int j0 = st * 16 + quad * 4 + 15 - ln;
#pragma unroll
            for (int r = 0; r < 4; ++r) {
                float v = (cac[st][r] + gw[ln * 80 + j0 + r]) * 0.125f;
                int ss = st * 16 + quad * 4 + r;
                v = ((bits >> ss) & 1ull) ? v : -1.0e30f;
                sc[st][r] = v;
                cmax = fmaxf(cmax, v);
            }
        }
        cmax = fmaxf(cmax, __shfl_xor(cmax, 16));
        cmax = fmaxf(cmax, __shfl_xor(cmax, 32));
        float m_new = fmaxf(m_run, cmax);
        float alpha = __expf(m_run - m_new);
        float psum = 0.f;
#pragma unroll
        for (int st = 0; st < 4; ++st) {
            float p0 = __expf(sc[st][0] - m_new);
            float p1 = __expf(sc[st][1] - m_new);
            float p2 = __expf(sc[st][2] - m_new);
            float p3 = __expf(sc[st][3] - m_new);
            psum += (p0 + p1) + (p2 + p3);
            ushort4 pk;
            pk.x = f2b(p0); pk.y = f2b(p1); pk.z = f2b(p2); pk.w = f2b(p3);
            *(ushort4*)&Prob[w][ln * 72 + st * 16 + quad * 4] = pk;
        }
        psum += __shfl_xor(psum, 16);
        psum += __shfl_xor(psum, 32);
        l_run = l_run * alpha + psum;
        m_run = m_new;
        float a0s = __shfl(alpha, quad * 4 + 0);
        float a1s = __shfl(alpha, quad * 4 + 1);
        float a2s = __shfl(alpha, quad * 4 + 2);
        float a3s = __shfl(alpha, quad * 4 + 3);
        O0[0] *= a0s; O0[1] *= a1s; O0[2] *= a2s; O0[3] *= a3s;
        O1[0] *= a0s; O1[1] *= a1s; O1[2] *= a2s; O1[3] *= a3s;
        O2[0] *= a0s; O2[1] *= a1s; O2[2] *= a2s; O2[3] *= a3s;
        O3[0] *= a0s; O3[1] *= a1s; O3[2] *= a2s; O3[3] *= a3s;
        // PV
        bf16x8 pa0 = *(bf16x8*)&Prob[w][ln * 72 + quad * 8];
        bf16x8 pa1 = *(bf16x8*)&Prob[w][ln * 72 + 32 + quad * 8];
        {
            bf16x8 v0 = *(bf16x8*)&Vtlds[(0 + ln) * 72 + quad * 8];
            bf16x8 v1 = *(bf16x8*)&Vtlds[(0 + ln) * 72 + 32 + quad * 8];
            O0 = MFMA16(pa0, v0, O0); O0 = MFMA16(pa1, v1, O0);
        }
        {
            bf16x8 v0 = *(bf16x8*)&Vtlds[(16 + ln) * 72 + quad * 8];
            bf16x8 v1 = *(bf16x8*)&Vtlds[(16 + ln) * 72 + 32 + quad * 8];
            O1 = MFMA16(pa0, v0, O1); O1 = MFMA16(pa1, v1, O1);
        }
        {
            bf16x8 v0 = *(bf16x8*)&Vtlds[(32 + ln) * 72 + quad * 8];
            bf16x8 v1 = *(bf16x8*)&Vtlds[(32 + ln) * 72 + 32 + quad * 8];
            O2 = MFMA16(pa0, v0, O2); O2 = MFMA16(pa1, v1, O2);
        }
        {
            bf16x8 v0 = *(bf16x8*)&Vtlds[(48 + ln) * 72 + quad * 8];
            bf16x8 v1 = *(bf16x8*)&Vtlds[(48 + ln) * 72 + 32 + quad * 8];
            O3 = MFMA16(pa0, v0, O3); O3 = MFMA16(pa1, v1, O3);
        }
    }
    float li0 = 1.0f / __shfl(l_run, quad * 4 + 0);
    float li1 = 1.0f / __shfl(l_run, quad * 4 + 1);
    float li2 = 1.0f / __shfl(l_run, quad * 4 + 2);
    float li3 = 1.0f / __shfl(l_run, quad * 4 + 3);
    float li[4] = {li0, li1, li2, li3};
#pragma unroll
    for (int r = 0; r < 4; ++r) {
        size_t zo = ((size_t)b * 1024 + t0 + 16 * w + quad * 4 + r) * 512 + h * 64 + ln;
        Z[zo + 0]  = f2b(O0[r] * li[r]);
        Z[zo + 16] = f2b(O1[r] * li[r]);
        Z[zo + 32] = f2b(O2[r] * li[r]);
        Z[zo + 48] = f2b(O3[r] * li[r]);
    }
}

// ---------------------------------------------------------------- out MFMA
__global__ __launch_bounds__(256, 2) void out_mfma(
    const u16* __restrict__ Zb, const u16* __restrict__ WoT,
    float* __restrict__ out)
{
    __shared__ u16 Xl[128 * 40];
    __shared__ u16 Wl[128 * 40];
    const int tid = threadIdx.x;
    const int lane = tid & 63, w = tid >> 6;
    const int quad = lane >> 4, ln = lane & 15;
    const int wm = w & 1, wn = w >> 1;
    const int m0 = blockIdx.x * 128;
    const int n0 = blockIdx.y * 128;

    floatx4 acc[4][4];
#pragma unroll
    for (int i = 0; i < 4; ++i)
#pragma unroll
        for (int j = 0; j < 4; ++j) acc[i][j] = (floatx4){0.f, 0.f, 0.f, 0.f};

    for (int kc = 0; kc < 512; kc += 32) {
        __syncthreads();
#pragma unroll
        for (int it = 0; it < 2; ++it) {
            int idx = tid + (it << 8);
            int r = idx >> 2, g = idx & 3;
            *(ushort8v*)&Xl[r * 40 + g * 8] =
                *(const ushort8v*)&Zb[(size_t)(m0 + r) * 512 + kc + g * 8];
            *(ushort8v*)&Wl[r * 40 + g * 8] =
                *(const ushort8v*)&WoT[(size_t)(n0 + r) * 512 + kc + g * 8];
        }
        __syncthreads();
        bf16x8 am[4], an[4];
#pragma unroll
        for (int i = 0; i < 4; ++i)
            am[i] = *(bf16x8*)&Xl[(wm * 64 + i * 16 + ln) * 40 + quad * 8];
#pragma unroll
        for (int j = 0; j < 4; ++j)
            an[j] = *(bf16x8*)&Wl[(wn * 64 + j * 16 + ln) * 40 + quad * 8];
#pragma unroll
        for (int i = 0; i < 4; ++i)
#pragma unroll
            for (int j = 0; j < 4; ++j)
                acc[i][j] = MFMA16(an[j], am[i], acc[i][j]);
    }
#pragma unroll
    for (int i = 0; i < 4; ++i) {
        int m = m0 + wm * 64 + i * 16 + ln;
#pragma unroll
        for (int j = 0; j < 4; ++j) {
            int n = n0 + wn * 64 + j * 16 + quad * 4;
            float4 s;
            s.x = acc[i][j][0]; s.y = acc[i][j][1];
            s.z = acc[i][j][2]; s.w = acc[i][j][3];
            *(float4*)&out[(size_t)m * 512 + n] = s;
        }
    }
}

// ---------------------------------------------------------------- launch
extern "C" void kernel_launch(void* const* d_in, const int* in_sizes, int n_in,
                              void* d_out, int out_size, void* d_ws, size_t ws_size,
                              hipStream_t stream) {
    const float* xs   = (const float*)d_in[0];
    const int*   mask = (const int*)d_in[1];
    const float* Wq   = (const float*)d_in[2];
    const float* Wk   = (const float*)d_in[3];
    const float* Wv   = (const float*)d_in[4];
    const float* Wpos = (const float*)d_in[5];
    const float* Wout = (const float*)d_in[6];
    const float* ub   = (const float*)d_in[7];
    const float* vb   = (const float*)d_in[8];
    float* out = (float*)d_out;

    // workspace (u16 elems unless noted), total ~38.8 MB
    u16* Qb  = (u16*)d_ws;                   // 4194304
    u16* Kb  = Qb + 4194304;                 // 4194304
    u16* Vtg = Kb + 4194304;                 // 4194304
    u16* P   = Vtg + 4194304;                // 1048576
    u16* XZ  = P + 1048576;                  // 4194304 (Xb, then reused as Z)
    u16* WT  = XZ + 4194304;                 // 4*262144
    u16* WqT = WT;
    u16* WkT = WT + 262144;
    u16* WvT = WT + 524288;
    u16* WoT = WT + 786432;
    u64* Mp  = (u64*)(WT + 1048576);         // 131072 u64 (8B-aligned)

    prep_kernel<<<4352, 256, 0, stream>>>(xs, XZ, Wq, Wk, Wv, Wout, WT, mask, Mp);
    pos_kernel<<<256, 256, 0, stream>>>(Wpos, P);
    qkv_mfma<<<dim3(64, 12), 256, 0, stream>>>(XZ, WqT, WkT, WvT, Qb, Kb, Vtg);
    attn_mfma<<<1024, 256, 0, stream>>>(Qb, Kb, Vtg, P, Mp, ub, vb, XZ);
    out_mfma<<<dim3(64, 4), 256, 0, stream>>>(XZ, WoT, out);
}

// Round 6
// 279.221 us; speedup vs baseline: 4.1306x; 1.0527x over previous
//
#include <hip/hip_runtime.h>
#include <hip/hip_bf16.h>

// Transformer-XL relative MHA. fp32 in/out, bf16 intermediates in d_ws.
// B=8 T=1024 D_MODEL=512 H=8 DH=64.
// R6: software-pipelined global->reg prefetch in attn/qkv/out chunk loops
// (hides VMEM latency behind compute; vmcnt drains after compute, not at the
// barrier). attn grid XCD-swizzled: bid&7 = XCD owns 8 (b,h) pairs -> K/V
// working set 2MB fits 4MB L2/XCD.
// Rel-shift identity: bd[t,s] = q_v[t] . p[1023 - t + s].

typedef unsigned short u16;
typedef unsigned long long u64;
typedef __attribute__((ext_vector_type(8))) short bf16x8;
typedef __attribute__((ext_vector_type(8))) unsigned short ushort8v;
typedef __attribute__((ext_vector_type(4))) float floatx4;

__device__ __forceinline__ float b2f(u16 u) {
    union { unsigned int i; float f; } x; x.i = ((unsigned int)u) << 16; return x.f;
}
__device__ __forceinline__ u16 f2b(float f) {
    __hip_bfloat16 h = __float2bfloat16(f);
    return *reinterpret_cast<u16*>(&h);
}

#define MFMA16(a, b, c) __builtin_amdgcn_mfma_f32_16x16x32_bf16(a, b, c, 0, 0, 0)

// ---------------------------------------------------------------- prep
// blocks [0,2048): castX ; [2048,2304): castW (4 matrices) ; [2304,4352): maskpack
__global__ __launch_bounds__(256) void prep_kernel(
    const float* __restrict__ X, u16* __restrict__ Xb,
    const float* __restrict__ W0, const float* __restrict__ W1,
    const float* __restrict__ W2, const float* __restrict__ W3,
    u16* __restrict__ WT,
    const int* __restrict__ mask, u64* __restrict__ Mp)
{
    const int bi = blockIdx.x;
    const int tid = threadIdx.x;
    if (bi < 2048) {
        size_t i = ((size_t)bi * 256 + tid) * 8;
        float4 a = *(const float4*)&X[i];
        float4 b = *(const float4*)&X[i + 4];
        ushort8v s;
        s[0] = f2b(a.x); s[1] = f2b(a.y); s[2] = f2b(a.z); s[3] = f2b(a.w);
        s[4] = f2b(b.x); s[5] = f2b(b.y); s[6] = f2b(b.z); s[7] = f2b(b.w);
        *(ushort8v*)&Xb[i] = s;
    } else if (bi < 2304) {
        __shared__ float t[64][68];
        const int li = bi - 2048;
        const int m = li >> 6;
        const float* src = (m == 0) ? W0 : (m == 1) ? W1 : (m == 2) ? W2 : W3;
        u16* dst = WT + (size_t)m * 262144;
        const int k0 = ((li >> 3) & 7) * 64, n0 = (li & 7) * 64;
        const int r = tid >> 4, c = tid & 15;
#pragma unroll
        for (int rr = 0; rr < 64; rr += 16) {
            float4 v = *(const float4*)&src[(size_t)(k0 + r + rr) * 512 + n0 + 4 * c];
            t[r + rr][4 * c + 0] = v.x;
            t[r + rr][4 * c + 1] = v.y;
            t[r + rr][4 * c + 2] = v.z;
            t[r + rr][4 * c + 3] = v.w;
        }
        __syncthreads();
        const int nrow = tid >> 2, kc = (tid & 3) * 16;
        ushort8v s0, s1;
#pragma unroll
        for (int e = 0; e < 8; ++e) {
            s0[e] = f2b(t[kc + e][nrow]);
            s1[e] = f2b(t[kc + 8 + e][nrow]);
        }
        *(ushort8v*)&dst[(size_t)(n0 + nrow) * 512 + k0 + kc] = s0;
        *(ushort8v*)&dst[(size_t)(n0 + nrow) * 512 + k0 + kc + 8] = s1;
    } else {
        const int lane = tid & 63, w = tid >> 6;
        const int row = (bi - 2304) * 4 + w;
#pragma unroll
        for (int j = 0; j < 16; ++j) {
            int v = mask[(size_t)row * 1024 + j * 64 + lane];
            u64 bits = __ballot(v != 0);
            if (lane == j) Mp[(size_t)row * 16 + j] = bits;
        }
    }
}

// ---------------------------------------------------------------- pos kernel
__global__ __launch_bounds__(256) void pos_kernel(const float* __restrict__ Wpos,
                                                  u16* __restrict__ P) {
    __shared__ float pe[8][512];
    const int tid = threadIdx.x;
    const int l0 = blockIdx.x * 8;
    float invf = expf(-9.210340371976184f * ((float)tid / 256.0f));
    for (int il = 0; il < 8; ++il) {
        int l = l0 + il; if (l > 2046) l = 2046;
        float ang = (float)(l - 1023) * invf;
        pe[il][2 * tid]     = sinf(ang);
        pe[il][2 * tid + 1] = cosf(ang);
    }
    __syncthreads();
    float acc[8][2];
    for (int il = 0; il < 8; ++il) { acc[il][0] = 0.f; acc[il][1] = 0.f; }
    for (int k = 0; k < 512; ++k) {
        float w0 = Wpos[k * 512 + tid];
        float w1 = Wpos[k * 512 + tid + 256];
#pragma unroll
        for (int il = 0; il < 8; ++il) {
            float pk = pe[il][k];
            acc[il][0] = fmaf(pk, w0, acc[il][0]);
            acc[il][1] = fmaf(pk, w1, acc[il][1]);
        }
    }
    for (int il = 0; il < 8; ++il) {
        int l = l0 + il; if (l >= 2047) break;
        int c0 = tid, c1 = tid + 256;
        P[((size_t)(c0 >> 6) * 2047 + l) * 64 + (c0 & 63)] = f2b(acc[il][0]);
        P[((size_t)(c1 >> 6) * 2047 + l) * 64 + (c1 & 63)] = f2b(acc[il][1]);
    }
}

// ---------------------------------------------------------------- qkv MFMA
// grid (64, 12): x -> 128 rows of xs; y: 0-3 Q, 4-7 K, 8-11 V (n0=(y&3)*128).
// Prefetch pipeline: load k-chunk i+1 into regs during compute of chunk i.
__global__ __launch_bounds__(256, 2) void qkv_mfma(
    const u16* __restrict__ Xb, const u16* __restrict__ WqT,
    const u16* __restrict__ WkT, const u16* __restrict__ WvT,
    u16* __restrict__ Qb, u16* __restrict__ Kb, u16* __restrict__ Vtg)
{
    __shared__ u16 Xl[128 * 40];
    __shared__ u16 Wl[128 * 40];
    const int tid = threadIdx.x;
    const int lane = tid & 63, w = tid >> 6;
    const int quad = lane >> 4, ln = lane & 15;
    const int wm = w & 1, wn = w >> 1;

    const int m0 = blockIdx.x * 128;
    const int sel = blockIdx.y >> 2;
    const int n0 = (blockIdx.y & 3) * 128;
    const u16* WT = (sel == 0) ? WqT : (sel == 1) ? WkT : WvT;
    const int b = m0 >> 10, tbase = m0 & 1023;

    const int sr = tid >> 2, sg = tid & 3;   // staging coords (rows 0..127 x2)

    floatx4 acc[4][4];
#pragma unroll
    for (int i = 0; i < 4; ++i)
#pragma unroll
        for (int j = 0; j < 4; ++j) acc[i][j] = (floatx4){0.f, 0.f, 0.f, 0.f};

    ushort8v xq[2], wq2[2];
#pragma unroll
    for (int it = 0; it < 2; ++it) {
        int r = sr + it * 64;
        xq[it]  = *(const ushort8v*)&Xb[(size_t)(m0 + r) * 512 + sg * 8];
        wq2[it] = *(const ushort8v*)&WT[(size_t)(n0 + r) * 512 + sg * 8];
    }

    for (int kc = 0; kc < 512; kc += 32) {
        __syncthreads();
#pragma unroll
        for (int it = 0; it < 2; ++it) {
            int r = sr + it * 64;
            *(ushort8v*)&Xl[r * 40 + sg * 8] = xq[it];
            *(ushort8v*)&Wl[r * 40 + sg * 8] = wq2[it];
        }
        __syncthreads();
        if (kc + 32 < 512) {
#pragma unroll
            for (int it = 0; it < 2; ++it) {
                int r = sr + it * 64;
                xq[it]  = *(const ushort8v*)&Xb[(size_t)(m0 + r) * 512 + kc + 32 + sg * 8];
                wq2[it] = *(const ushort8v*)&WT[(size_t)(n0 + r) * 512 + kc + 32 + sg * 8];
            }
        }
        bf16x8 am[4], an[4];
#pragma unroll
        for (int i = 0; i < 4; ++i)
            am[i] = *(bf16x8*)&Xl[(wm * 64 + i * 16 + ln) * 40 + quad * 8];
#pragma unroll
        for (int j = 0; j < 4; ++j)
            an[j] = *(bf16x8*)&Wl[(wn * 64 + j * 16 + ln) * 40 + quad * 8];
        if (sel < 2) {
#pragma unroll
            for (int i = 0; i < 4; ++i)
#pragma unroll
                for (int j = 0; j < 4; ++j)
                    acc[i][j] = MFMA16(an[j], am[i], acc[i][j]);
        } else {
#pragma unroll
            for (int i = 0; i < 4; ++i)
#pragma unroll
                for (int j = 0; j < 4; ++j)
                    acc[i][j] = MFMA16(am[i], an[j], acc[i][j]);
        }
    }
    if (sel < 2) {
        u16* dst = (sel == 0) ? Qb : Kb;
#pragma unroll
        for (int i = 0; i < 4; ++i) {
            int t = tbase + wm * 64 + i * 16 + ln;
#pragma unroll
            for (int j = 0; j < 4; ++j) {
                int n = n0 + wn * 64 + j * 16 + quad * 4;
                int h = n >> 6, d = n & 63;
                ushort4 s;
                s.x = f2b(acc[i][j][0]); s.y = f2b(acc[i][j][1]);
                s.z = f2b(acc[i][j][2]); s.w = f2b(acc[i][j][3]);
                *(ushort4*)&dst[(((size_t)b * 8 + h) * 1024 + t) * 64 + d] = s;
            }
        }
    } else {
#pragma unroll
        for (int i = 0; i < 4; ++i) {
            int t4 = tbase + wm * 64 + i * 16 + quad * 4;
#pragma unroll
            for (int j = 0; j < 4; ++j) {
                int n = n0 + wn * 64 + j * 16 + ln;
                int h = n >> 6, d = n & 63;
                ushort4 s;
                s.x = f2b(acc[i][j][0]); s.y = f2b(acc[i][j][1]);
                s.z = f2b(acc[i][j][2]); s.w = f2b(acc[i][j][3]);
                *(ushort4*)&Vtg[(((size_t)b * 8 + h) * 64 + d) * 1024 + t4] = s;
            }
        }
    }
}

// ---------------------------------------------------------------- attention
__device__ __forceinline__ bf16x8 addbias(bf16x8 q, const float* __restrict__ bias) {
    float4 a = *(const float4*)&bias[0];
    float4 b = *(const float4*)&bias[4];
    bf16x8 r;
    r[0] = (short)f2b(b2f((u16)q[0]) + a.x);
    r[1] = (short)f2b(b2f((u16)q[1]) + a.y);
    r[2] = (short)f2b(b2f((u16)q[2]) + a.z);
    r[3] = (short)f2b(b2f((u16)q[3]) + a.w);
    r[4] = (short)f2b(b2f((u16)q[4]) + b.x);
    r[5] = (short)f2b(b2f((u16)q[5]) + b.y);
    r[6] = (short)f2b(b2f((u16)q[6]) + b.z);
    r[7] = (short)f2b(b2f((u16)q[7]) + b.w);
    return r;
}

// Block = (b, h, 64 q-rows) = 4 waves x 16 rows. S-chunks of 64.
// bid&7 selects XCD-group: each owns 8 (b,h) pairs (K/V set = 2MB -> L2).
__global__ __launch_bounds__(256, 2) void attn_mfma(
    const u16* __restrict__ Qb,
    const u16* __restrict__ Kb, const u16* __restrict__ Vtg,
    const u16* __restrict__ P, const u64* __restrict__ Mp,
    const float* __restrict__ ub, const float* __restrict__ vb,
    u16* __restrict__ Z)
{
    __shared__ u16 Klds[64 * 72];          // [s][d] stride 72
    __shared__ u16 Vtlds[64 * 72];         // [d][s] stride 72
    __shared__ u16 Pb[128 * 64];           // [j][d] XOR-swizzled 16B blocks
    __shared__ float Gl[4][16 * 80];       // per wave: [tt][j] stride 80
    __shared__ u16 Prob[4][16 * 72];       // per wave: [tt][ss] stride 72

    const int tid  = threadIdx.x;
    const int lane = tid & 63;
    const int w    = tid >> 6;
    const int quad = lane >> 4;
    const int ln   = lane & 15;

    // XCD-aware decode: xg = bid&7 (XCD), idx = bid>>3; bh = xg*8 + idx>>4
    const int bid = blockIdx.x;
    const int xg  = bid & 7;
    const int idx = bid >> 3;
    const int bh_i = xg * 8 + (idx >> 4);
    const int t0 = (idx & 15) << 6;
    const int h  = bh_i & 7;
    const int b  = bh_i >> 3;
    const size_t bh  = (size_t)bh_i * 1024;
    const size_t bhd = (size_t)bh_i * 64;
    const size_t mprow = ((size_t)b * 1024 + t0 + 16 * w + ln) * 16;

    // register B-fragments with bias add (once per block)
    const size_t qoff = (bh + t0 + 16 * w + ln) * 64;
    const bf16x8 q0 = *(const bf16x8*)&Qb[qoff + quad * 8];
    const bf16x8 q1 = *(const bf16x8*)&Qb[qoff + 32 + quad * 8];
    const bf16x8 qu0 = addbias(q0, &ub[h * 64 + quad * 8]);
    const bf16x8 qu1 = addbias(q1, &ub[h * 64 + 32 + quad * 8]);
    const bf16x8 qv0 = addbias(q0, &vb[h * 64 + quad * 8]);
    const bf16x8 qv1 = addbias(q1, &vb[h * 64 + 32 + quad * 8]);

    floatx4 O0 = {0.f, 0.f, 0.f, 0.f}, O1 = O0, O2 = O0, O3 = O0;
    float m_run = -3.0e38f, l_run = 0.f;

    // staging coords
    const int str = tid >> 3, stg = tid & 7;   // rows 0..31 (x2), 0..127 (x4 for P)
    ushort8v kq[2], vq[2], pq[4];

#define LOAD_CHUNK(S0)                                                          \
    {                                                                           \
        _Pragma("unroll")                                                       \
        for (int it = 0; it < 2; ++it) {                                        \
            int r = str + it * 32;                                              \
            kq[it] = *(const ushort8v*)&Kb[(bh + (S0) + r) * 64 + stg * 8];     \
            vq[it] = *(const ushort8v*)&Vtg[(bhd + r) * 1024 + (S0) + stg * 8]; \
        }                                                                       \
        const int lb0 = 960 - t0 + (S0);                                        \
        _Pragma("unroll")                                                       \
        for (int it = 0; it < 4; ++it) {                                        \
            int r = str + it * 32;                                              \
            int l = lb0 + r; if (l > 2046) l = 2046;                            \
            pq[it] = *(const ushort8v*)&P[((size_t)h * 2047 + l) * 64 + stg * 8]; \
        }                                                                       \
    }

    LOAD_CHUNK(0)

    for (int s0 = 0; s0 < 1024; s0 += 64) {
        __syncthreads();
#pragma unroll
        for (int it = 0; it < 2; ++it) {
            int r = str + it * 32;
            *(ushort8v*)&Klds[r * 72 + stg * 8] = kq[it];
            *(ushort8v*)&Vtlds[r * 72 + stg * 8] = vq[it];
        }
#pragma unroll
        for (int it = 0; it < 4; ++it) {
            int r = str + it * 32;
            *(ushort8v*)&Pb[r * 64 + ((stg ^ (r & 7)) << 3)] = pq[it];
        }
        const u64 bits = Mp[mprow + (s0 >> 6)];
        __syncthreads();
        if (s0 + 64 < 1024) LOAD_CHUNK(s0 + 64)

        // BD: G^T[j][tt] = Pband . Qv^T  (j = ss - tt + 15)
        float* gw = &Gl[w][0];
#pragma unroll
        for (int jt = 0; jt < 5; ++jt) {
            int jr = 48 - 16 * w + jt * 16 + ln;
            floatx4 g = {0.f, 0.f, 0.f, 0.f};
            bf16x8 a0 = *(bf16x8*)&Pb[jr * 64 + ((quad ^ (jr & 7)) << 3)];
            bf16x8 a1 = *(bf16x8*)&Pb[jr * 64 + (((4 + quad) ^ (jr & 7)) << 3)];
            g = MFMA16(a0, qv0, g);
            g = MFMA16(a1, qv1, g);
            *(floatx4*)&gw[ln * 80 + jt * 16 + quad * 4] = g;
        }
        // AC: S^T[ss][tt] = K . Qu^T
        floatx4 cac[4];
#pragma unroll
        for (int st = 0; st < 4; ++st) {
            floatx4 c = {0.f, 0.f, 0.f, 0.f};
            int kr = st * 16 + ln;
            bf16x8 a0 = *(bf16x8*)&Klds[kr * 72 + quad * 8];
            bf16x8 a1 = *(bf16x8*)&Klds[kr * 72 + 32 + quad * 8];
            c = MFMA16(a0, qu0, c);
            c = MFMA16(a1, qu1, c);
            cac[st] = c;
        }
        // scores + online softmax (lane owns col tt = ln)
        float sc[4][4];
        float cmax = -3.0e38f;
#pragma unroll
        for (int st = 0; st < 4; ++st) {
            int j0 = st * 16 + quad * 4 + 15 - ln;
#pragma unroll
            for (int r = 0; r < 4; ++r) {
                float v = (cac[st][r] + gw[ln * 80 + j0 + r]) * 0.125f;
                int ss = st * 16 + quad * 4 + r;
                v = ((bits >> ss) & 1ull) ? v : -1.0e30f;
                sc[st][r] = v;
                cmax = fmaxf(cmax, v);
            }
        }
        cmax = fmaxf(cmax, __shfl_xor(cmax, 16));
        cmax = fmaxf(cmax, __shfl_xor(cmax, 32));
        float m_new = fmaxf(m_run, cmax);
        float alpha = __expf(m_run - m_new);
        float psum = 0.f;
#pragma unroll
        for (int st = 0; st < 4; ++st) {
            float p0 = __expf(sc[st][0] - m_new);
            float p1 = __expf(sc[st][1] - m_new);
            float p2 = __expf(sc[st][2] - m_new);
            float p3 = __expf(sc[st][3] - m_new);
            psum += (p0 + p1) + (p2 + p3);
            ushort4 pk;
            pk.x = f2b(p0); pk.y = f2b(p1); pk.z = f2b(p2); pk.w = f2b(p3);
            *(ushort4*)&Prob[w][ln * 72 + st * 16 + quad * 4] = pk;
        }
        psum += __shfl_xor(psum, 16);
        psum += __shfl_xor(psum, 32);
        l_run = l_run * alpha + psum;
        m_run = m_new;
        float a0s = __shfl(alpha, quad * 4 + 0);
        float a1s = __shfl(alpha, quad * 4 + 1);
        float a2s = __shfl(alpha, quad * 4 + 2);
        float a3s = __shfl(alpha, quad * 4 + 3);
        O0[0] *= a0s; O0[1] *= a1s; O0[2] *= a2s; O0[3] *= a3s;
        O1[0] *= a0s; O1[1] *= a1s; O1[2] *= a2s; O1[3] *= a3s;
        O2[0] *= a0s; O2[1] *= a1s; O2[2] *= a2s; O2[3] *= a3s;
        O3[0] *= a0s; O3[1] *= a1s; O3[2] *= a2s; O3[3] *= a3s;
        // PV
        bf16x8 pa0 = *(bf16x8*)&Prob[w][ln * 72 + quad * 8];
        bf16x8 pa1 = *(bf16x8*)&Prob[w][ln * 72 + 32 + quad * 8];
        {
            bf16x8 v0 = *(bf16x8*)&Vtlds[(0 + ln) * 72 + quad * 8];
            bf16x8 v1 = *(bf16x8*)&Vtlds[(0 + ln) * 72 + 32 + quad * 8];
            O0 = MFMA16(pa0, v0, O0); O0 = MFMA16(pa1, v1, O0);
        }
        {
            bf16x8 v0 = *(bf16x8*)&Vtlds[(16 + ln) * 72 + quad * 8];
            bf16x8 v1 = *(bf16x8*)&Vtlds[(16 + ln) * 72 + 32 + quad * 8];
            O1 = MFMA16(pa0, v0, O1); O1 = MFMA16(pa1, v1, O1);
        }
        {
            bf16x8 v0 = *(bf16x8*)&Vtlds[(32 + ln) * 72 + quad * 8];
            bf16x8 v1 = *(bf16x8*)&Vtlds[(32 + ln) * 72 + 32 + quad * 8];
            O2 = MFMA16(pa0, v0, O2); O2 = MFMA16(pa1, v1, O2);
        }
        {
            bf16x8 v0 = *(bf16x8*)&Vtlds[(48 + ln) * 72 + quad * 8];
            bf16x8 v1 = *(bf16x8*)&Vtlds[(48 + ln) * 72 + 32 + quad * 8];
            O3 = MFMA16(pa0, v0, O3); O3 = MFMA16(pa1, v1, O3);
        }
    }
    float li0 = 1.0f / __shfl(l_run, quad * 4 + 0);
    float li1 = 1.0f / __shfl(l_run, quad * 4 + 1);
    float li2 = 1.0f / __shfl(l_run, quad * 4 + 2);
    float li3 = 1.0f / __shfl(l_run, quad * 4 + 3);
    float li[4] = {li0, li1, li2, li3};
#pragma unroll
    for (int r = 0; r < 4; ++r) {
        size_t zo = ((size_t)b * 1024 + t0 + 16 * w + quad * 4 + r) * 512 + h * 64 + ln;
        Z[zo + 0]  = f2b(O0[r] * li[r]);
        Z[zo + 16] = f2b(O1[r] * li[r]);
        Z[zo + 32] = f2b(O2[r] * li[r]);
        Z[zo + 48] = f2b(O3[r] * li[r]);
    }
}

// ---------------------------------------------------------------- out MFMA
__global__ __launch_bounds__(256, 2) void out_mfma(
    const u16* __restrict__ Zb, const u16* __restrict__ WoT,
    float* __restrict__ out)
{
    __shared__ u16 Xl[128 * 40];
    __shared__ u16 Wl[128 * 40];
    const int tid = threadIdx.x;
    const int lane = tid & 63, w = tid >> 6;
    const int quad = lane >> 4, ln = lane & 15;
    const int wm = w & 1, wn = w >> 1;
    const int m0 = blockIdx.x * 128;
    const int n0 = blockIdx.y * 128;
    const int sr = tid >> 2, sg = tid & 3;

    floatx4 acc[4][4];
#pragma unroll
    for (int i = 0; i < 4; ++i)
#pragma unroll
        for (int j = 0; j < 4; ++j) acc[i][j] = (floatx4){0.f, 0.f, 0.f, 0.f};

    ushort8v xq[2], wq2[2];
#pragma unroll
    for (int it = 0; it < 2; ++it) {
        int r = sr + it * 64;
        xq[it]  = *(const ushort8v*)&Zb[(size_t)(m0 + r) * 512 + sg * 8];
        wq2[it] = *(const ushort8v*)&WoT[(size_t)(n0 + r) * 512 + sg * 8];
    }

    for (int kc = 0; kc < 512; kc += 32) {
        __syncthreads();
#pragma unroll
        for (int it = 0; it < 2; ++it) {
            int r = sr + it * 64;
            *(ushort8v*)&Xl[r * 40 + sg * 8] = xq[it];
            *(ushort8v*)&Wl[r * 40 + sg * 8] = wq2[it];
        }
        __syncthreads();
        if (kc + 32 < 512) {
#pragma unroll
            for (int it = 0; it < 2; ++it) {
                int r = sr + it * 64;
                xq[it]  = *(const ushort8v*)&Zb[(size_t)(m0 + r) * 512 + kc + 32 + sg * 8];
                wq2[it] = *(const ushort8v*)&WoT[(size_t)(n0 + r) * 512 + kc + 32 + sg * 8];
            }
        }
        bf16x8 am[4], an[4];
#pragma unroll
        for (int i = 0; i < 4; ++i)
            am[i] = *(bf16x8*)&Xl[(wm * 64 + i * 16 + ln) * 40 + quad * 8];
#pragma unroll
        for (int j = 0; j < 4; ++j)
            an[j] = *(bf16x8*)&Wl[(wn * 64 + j * 16 + ln) * 40 + quad * 8];
#pragma unroll
        for (int i = 0; i < 4; ++i)
#pragma unroll
            for (int j = 0; j < 4; ++j)
                acc[i][j] = MFMA16(an[j], am[i], acc[i][j]);
    }
#pragma unroll
    for (int i = 0; i < 4; ++i) {
        int m = m0 + wm * 64 + i * 16 + ln;
#pragma unroll
        for (int j = 0; j < 4; ++j) {
            int n = n0 + wn * 64 + j * 16 + quad * 4;
            float4 s;
            s.x = acc[i][j][0]; s.y = acc[i][j][1];
            s.z = acc[i][j][2]; s.w = acc[i][j][3];
            *(float4*)&out[(size_t)m * 512 + n] = s;
        }
    }
}

// ---------------------------------------------------------------- launch
extern "C" void kernel_launch(void* const* d_in, const int* in_sizes, int n_in,
                              void* d_out, int out_size, void* d_ws, size_t ws_size,
                              hipStream_t stream) {
    const float* xs   = (const float*)d_in[0];
    const int*   mask = (const int*)d_in[1];
    const float* Wq   = (const float*)d_in[2];
    const float* Wk   = (const float*)d_in[3];
    const float* Wv   = (const float*)d_in[4];
    const float* Wpos = (const float*)d_in[5];
    const float* Wout = (const float*)d_in[6];
    const float* ub   = (const float*)d_in[7];
    const float* vb   = (const float*)d_in[8];
    float* out = (float*)d_out;

    u16* Qb  = (u16*)d_ws;                   // 4194304
    u16* Kb  = Qb + 4194304;                 // 4194304
    u16* Vtg = Kb + 4194304;                 // 4194304
    u16* P   = Vtg + 4194304;                // 1048576
    u16* XZ  = P + 1048576;                  // 4194304 (Xb, then reused as Z)
    u16* WT  = XZ + 4194304;                 // 4*262144
    u16* WqT = WT;
    u16* WkT = WT + 262144;
    u16* WvT = WT + 524288;
    u16* WoT = WT + 786432;
    u64* Mp  = (u64*)(WT + 1048576);         // 131072 u64

    prep_kernel<<<4352, 256, 0, stream>>>(xs, XZ, Wq, Wk, Wv, Wout, WT, mask, Mp);
    pos_kernel<<<256, 256, 0, stream>>>(Wpos, P);
    qkv_mfma<<<dim3(64, 12), 256, 0, stream>>>(XZ, WqT, WkT, WvT, Qb, Kb, Vtg);
    attn_mfma<<<1024, 256, 0, stream>>>(Qb, Kb, Vtg, P, Mp, ub, vb, XZ);
    out_mfma<<<dim3(64, 4), 256, 0, stream>>>(XZ, WoT, out);
}